// Round 1
// baseline (306.683 us; speedup 1.0000x reference)
//
#include <hip/hip_runtime.h>
#include <hip/hip_bf16.h>
#include <math.h>

typedef unsigned short U16;
typedef unsigned int U32;
typedef __attribute__((ext_vector_type(8))) short bf8;        // 8 x bf16 (MFMA A/B frag)
typedef __attribute__((ext_vector_type(4))) float f4;         // MFMA C/D frag
typedef __attribute__((ext_vector_type(4))) unsigned short u16x4;

#define AS1 __attribute__((address_space(1)))
#define AS3 __attribute__((address_space(3)))

// ---- constants ----
#define BSZ   256
#define NTOK  196
#define NQ    49
#define INDIM 384
#define OUTD  512
#define NH    12
#define HKD   32
#define DV    64
#define DHD   768
#define KVH   1152
#define NPAD  224      // PV K padded to 7*32
#define PST   232      // plds row stride (u16), 16B-aligned rows, conflict-friendly

__device__ inline U16 f2bf(float f){
    union { float f; U32 u; } v; v.f = f;
    U32 r = v.u + 0x7FFFu + ((v.u >> 16) & 1u);   // RNE
    return (U16)(r >> 16);
}
__device__ inline f4 f4zero(){ f4 z; z[0]=0.f; z[1]=0.f; z[2]=0.f; z[3]=0.f; return z; }
__device__ inline bf8 bf8zero(){ bf8 v; 
#pragma unroll
    for (int j=0;j<8;++j) v[j]=0; return v; }

// ---------------- prep kernels ----------------
__global__ void k_cast8(const float* __restrict__ in, U16* __restrict__ out, int n8){
    int i = blockIdx.x*256 + threadIdx.x;
    if (i >= n8) return;
    const float* p = in + (size_t)i*8;
    U16 o[8];
#pragma unroll
    for (int j=0;j<8;++j) o[j] = f2bf(p[j]);
    *(bf8*)(out + (size_t)i*8) = *(const bf8*)o;
}

__global__ void k_castxs(const float* __restrict__ x, U16* __restrict__ out, int n8){
    int i = blockIdx.x*256 + threadIdx.x;
    if (i >= n8) return;
    int row = i / 48;          // 48 = 384/8
    int c8  = i - row*48;
    int b   = row / 49;
    int q   = row - b*49;
    int r_  = q / 7, c_ = q - r_*7;
    const float* p = x + ((size_t)(b*NTOK + 28*r_ + 2*c_))*INDIM + c8*8;
    U16 o[8];
#pragma unroll
    for (int j=0;j<8;++j) o[j] = f2bf(p[j]);
    *(bf8*)(out + (size_t)i*8) = *(const bf8*)o;
}

__global__ void k_cast1(const float* __restrict__ in, U16* __restrict__ out, int n){
    int i = blockIdx.x*256 + threadIdx.x;
    if (i < n) out[i] = f2bf(in[i]);
}

__global__ void k_bn(const float* __restrict__ g, const float* __restrict__ b,
                     const float* __restrict__ m, const float* __restrict__ v,
                     float* __restrict__ s_out, float* __restrict__ b_out, int n){
    int i = blockIdx.x*256 + threadIdx.x;
    if (i >= n) return;
    float s = g[i] / sqrtf(v[i] + 1e-5f);
    s_out[i] = s;
    b_out[i] = b[i] - m[i]*s;
}

__global__ void k_bias(const float* __restrict__ ab, const int* __restrict__ idxs,
                       float* __restrict__ out, int n, int n_off){
    int i = blockIdx.x*256 + threadIdx.x;
    if (i >= n) return;
    int h = i / (NQ*NTOK);
    int qk = i - h*(NQ*NTOK);
    out[i] = ab[h*n_off + idxs[qk]];
}

__global__ void k_vtz(U16* __restrict__ vt, int n){   // zero v_t pad cols [196,224)
    int i = blockIdx.x*256 + threadIdx.x;
    if (i >= n) return;
    int bd = i / 28;
    int c  = i - bd*28;
    vt[(size_t)bd*NPAD + NTOK + c] = 0;
}

// ---------------- 128x128x32 bf16 GEMM (B^T weights), templated epilogue ----------------
// EPI 0: kv split (k + v-transposed)   EPI 1: q bf16 store   EPI 2: proj f32 store
template<int EPI>
__global__ __launch_bounds__(256) void k_gemm(
    const U16* __restrict__ A, const U16* __restrict__ Bw,
    const float* __restrict__ s_arr, const float* __restrict__ b_arr,
    U16* __restrict__ o16a, U16* __restrict__ o16b, float* __restrict__ o32,
    int M, int N, int K)
{
    __shared__ U16 As[128*32];
    __shared__ U16 Bs[128*32];
    const int tid  = threadIdx.x;
    const int lane = tid & 63;
    const int w    = tid >> 6;
    const int wm   = w >> 1, wn = w & 1;
    const int l15  = lane & 15, oct = lane >> 4;
    const int gm0  = blockIdx.x * 128;
    const int gn0  = blockIdx.y * 128;

    f4 acc[4][4];
#pragma unroll
    for (int i=0;i<4;++i)
#pragma unroll
        for (int j=0;j<4;++j) acc[i][j] = f4zero();

    const int srow = lane >> 2;        // 0..15
    const int scol = (lane & 3) * 8;   // u16 units (16B chunks)
    const int nk = K >> 5;

    for (int kt = 0; kt < nk; ++kt){
        const int kb = kt*32;
#pragma unroll
        for (int c=0;c<2;++c){
            int rg = 2*w + c;          // 0..7 (16 rows each)
            const U16* ga = A  + (size_t)(gm0 + rg*16 + srow)*K + kb + scol;
            __builtin_amdgcn_global_load_lds((const AS1 U32*)ga,
                (AS3 U32*)(As + rg*512 + lane*8), 16, 0, 0);
            const U16* gb = Bw + (size_t)(gn0 + rg*16 + srow)*K + kb + scol;
            __builtin_amdgcn_global_load_lds((const AS1 U32*)gb,
                (AS3 U32*)(Bs + rg*512 + lane*8), 16, 0, 0);
        }
        __syncthreads();
        bf8 af[4], bfr[4];
#pragma unroll
        for (int i=0;i<4;++i) af[i]  = *(const bf8*)(As + (wm*64 + i*16 + l15)*32 + oct*8);
#pragma unroll
        for (int j=0;j<4;++j) bfr[j] = *(const bf8*)(Bs + (wn*64 + j*16 + l15)*32 + oct*8);
#pragma unroll
        for (int i=0;i<4;++i)
#pragma unroll
            for (int j=0;j<4;++j)
                acc[i][j] = __builtin_amdgcn_mfma_f32_16x16x32_bf16(af[i], bfr[j], acc[i][j], 0, 0, 0);
        __syncthreads();
    }

    // epilogue: BN fold, then store per variant
#pragma unroll
    for (int j=0;j<4;++j){
        const int col = gn0 + wn*64 + j*16 + l15;
        const float sc = s_arr[col];
        const float bi = b_arr[col];
#pragma unroll
        for (int i=0;i<4;++i){
            const int row0 = gm0 + wm*64 + i*16 + oct*4;
#pragma unroll
            for (int r=0;r<4;++r){
                const float val = acc[i][j][r]*sc + bi;
                const int row = row0 + r;
                if (EPI == 0){
                    int h  = col / 96, rr = col - h*96;
                    int bb = row / NTOK, n = row - bb*NTOK;
                    if (rr < HKD)
                        o16a[(((size_t)(bb*NH + h))*NTOK + n)*HKD + rr] = f2bf(val);
                    else
                        o16b[(((size_t)(bb*NH + h))*DV + (rr - HKD))*NPAD + n] = f2bf(val);
                } else if (EPI == 1){
                    o16a[(size_t)row*INDIM + col] = f2bf(val);
                } else {
                    o32[(size_t)row*OUTD + col] = val;
                }
            }
        }
    }
}

// ---------------- fused attention: one block per (b,h), 4 waves x 16 q-cols ----------------
__global__ __launch_bounds__(256) void k_attn(
    const U16* __restrict__ qbf, const U16* __restrict__ kbf, const U16* __restrict__ vt,
    const float* __restrict__ bias_full, U16* __restrict__ aout)
{
    __shared__ U16 plds[64*PST];
    const int bh = blockIdx.x;
    const int b  = bh / NH, h = bh - b*NH;
    const int tid = threadIdx.x, lane = tid & 63, w = tid >> 6;
    const int l15 = lane & 15, oct = lane >> 4;

    // q fragment (B operand, col = l15): this lane's q index
    const int qg = w*16 + l15;
    bf8 qf = bf8zero();
    if (qg < NQ) qf = *(const bf8*)(qbf + ((size_t)(b*NQ + qg))*INDIM + h*HKD + oct*8);

    // QK^T swapped: C = attn^T tiles (rows = n, cols = q)
    f4 acc[13];
#pragma unroll
    for (int mt=0;mt<13;++mt) acc[mt] = f4zero();
#pragma unroll
    for (int mt=0;mt<13;++mt){
        int n = mt*16 + l15;
        bf8 kf = bf8zero();
        if (n < NTOK) kf = *(const bf8*)(kbf + ((size_t)bh*NTOK + n)*HKD + oct*8);
        acc[mt] = __builtin_amdgcn_mfma_f32_16x16x32_bf16(kf, qf, acc[mt], 0, 0, 0);
    }

    const float scale = 0.17677669529663689f;   // 1/sqrt(32)
    float mx = -1e30f;
#pragma unroll
    for (int mt=0;mt<13;++mt){
#pragma unroll
        for (int r=0;r<4;++r){
            int n = mt*16 + oct*4 + r;
            float s;
            if (n < NTOK){
                float bi = (qg < NQ) ? bias_full[((size_t)h*NQ + qg)*NTOK + n] : 0.f;
                s = acc[mt][r]*scale + bi;
            } else s = -1e30f;
            acc[mt][r] = s;
            mx = fmaxf(mx, s);
        }
    }
    mx = fmaxf(mx, __shfl_xor(mx, 16));
    mx = fmaxf(mx, __shfl_xor(mx, 32));

    float sum = 0.f;
#pragma unroll
    for (int mt=0;mt<13;++mt){
#pragma unroll
        for (int r=0;r<4;++r){
            int n = mt*16 + oct*4 + r;
            float p = (n < NTOK) ? __expf(acc[mt][r] - mx) : 0.f;
            acc[mt][r] = p;
            sum += p;
        }
    }
    sum += __shfl_xor(sum, 16);
    sum += __shfl_xor(sum, 32);
    const float inv = 1.f / sum;

    // write P (bf16) into LDS in PV A-fragment layout: row = q (this lane's l15 row), cols n
    const int prow = w*16 + l15;
#pragma unroll
    for (int mt=0;mt<13;++mt){
        u16x4 pk;
#pragma unroll
        for (int r=0;r<4;++r) pk[r] = f2bf(acc[mt][r]*inv);
        *(u16x4*)(plds + prow*PST + mt*16 + oct*4) = pk;
    }
    if (oct == 0){
#pragma unroll
        for (int c=208;c<224;++c) plds[prow*PST + c] = 0;
    }
    __syncthreads();

    // PV: out(q,d) = P(q,n) @ v(n,d); A from LDS, B = v^T (b,h,d,n) from global
    f4 pacc[4];
#pragma unroll
    for (int dt=0;dt<4;++dt) pacc[dt] = f4zero();
#pragma unroll
    for (int kt=0;kt<7;++kt){
        bf8 pa = *(const bf8*)(plds + prow*PST + kt*32 + oct*8);
#pragma unroll
        for (int dt=0;dt<4;++dt){
            bf8 vf = *(const bf8*)(vt + ((size_t)bh*DV + dt*16 + l15)*NPAD + kt*32 + oct*8);
            pacc[dt] = __builtin_amdgcn_mfma_f32_16x16x32_bf16(pa, vf, pacc[dt], 0, 0, 0);
        }
    }

    // epilogue: hard_swish, store bf16 (b, q, h*64+d)
#pragma unroll
    for (int dt=0;dt<4;++dt){
#pragma unroll
        for (int r=0;r<4;++r){
            int qo = w*16 + oct*4 + r;
            if (qo < NQ){
                int d = dt*16 + l15;
                float v = pacc[dt][r];
                float t = fminf(fmaxf(v + 3.f, 0.f), 6.f);
                aout[((size_t)(b*NQ + qo))*DHD + h*DV + d] = f2bf(v * t * (1.f/6.f));
            }
        }
    }
}

// ---------------- launch ----------------
extern "C" void kernel_launch(void* const* d_in, const int* in_sizes, int n_in,
                              void* d_out, int out_size, void* d_ws, size_t ws_size,
                              hipStream_t stream)
{
    const float* x    = (const float*)d_in[0];
    const float* kv_w = (const float*)d_in[1];
    const float* kv_g = (const float*)d_in[2];
    const float* kv_b = (const float*)d_in[3];
    const float* kv_m = (const float*)d_in[4];
    const float* kv_v = (const float*)d_in[5];
    const float* q_w  = (const float*)d_in[6];
    const float* q_g  = (const float*)d_in[7];
    const float* q_b  = (const float*)d_in[8];
    const float* q_m  = (const float*)d_in[9];
    const float* q_v  = (const float*)d_in[10];
    const float* pr_w = (const float*)d_in[11];
    const float* pr_g = (const float*)d_in[12];
    const float* pr_b = (const float*)d_in[13];
    const float* pr_m = (const float*)d_in[14];
    const float* pr_v = (const float*)d_in[15];
    const float* ab   = (const float*)d_in[16];
    const int*  idxs  = (const int*)d_in[17];
    const int n_off = in_sizes[16] / NH;

    char* ws = (char*)d_ws;
    size_t off = 0;
    auto alloc = [&](size_t bytes)->char*{
        char* p = ws + off; off += (bytes + 255) & ~(size_t)255; return p;
    };
    U16*   x_bf   = (U16*)  alloc((size_t)BSZ*NTOK*INDIM*2);   // 38.5 MB
    U16*   xs_bf  = (U16*)  alloc((size_t)BSZ*NQ*INDIM*2);     // 9.6 MB
    U16*   kvw_bf = (U16*)  alloc((size_t)KVH*INDIM*2);
    U16*   qw_bf  = (U16*)  alloc((size_t)INDIM*INDIM*2);
    U16*   prw_bf = (U16*)  alloc((size_t)OUTD*DHD*2);
    float* s_kv   = (float*)alloc(KVH*4);
    float* b_kv   = (float*)alloc(KVH*4);
    float* s_q    = (float*)alloc(INDIM*4);
    float* b_q    = (float*)alloc(INDIM*4);
    float* s_pr   = (float*)alloc(OUTD*4);
    float* b_pr   = (float*)alloc(OUTD*4);
    float* biasf  = (float*)alloc((size_t)NH*NQ*NTOK*4);
    U16*   k_bf   = (U16*)  alloc((size_t)BSZ*NH*NTOK*HKD*2);  // 38.5 MB
    U16*   v_t    = (U16*)  alloc((size_t)BSZ*NH*DV*NPAD*2);   // 88 MB
    U16*   q_out  = (U16*)  alloc((size_t)BSZ*NQ*INDIM*2);     // 9.6 MB
    U16*   a_out  = (U16*)  alloc((size_t)BSZ*NQ*DHD*2);       // 19.3 MB
    if (off > ws_size) return;  // insufficient workspace: fail visibly (no OOB writes)

    // prep
    {
        int n8 = BSZ*NTOK*INDIM/8;
        k_cast8<<<(n8+255)/256, 256, 0, stream>>>(x, x_bf, n8);
    }
    {
        int n8 = BSZ*NQ*INDIM/8;
        k_castxs<<<(n8+255)/256, 256, 0, stream>>>(x, xs_bf, n8);
    }
    k_cast1<<<(KVH*INDIM+255)/256, 256, 0, stream>>>(kv_w, kvw_bf, KVH*INDIM);
    k_cast1<<<(INDIM*INDIM+255)/256, 256, 0, stream>>>(q_w, qw_bf, INDIM*INDIM);
    k_cast1<<<(OUTD*DHD+255)/256, 256, 0, stream>>>(pr_w, prw_bf, OUTD*DHD);
    k_bn<<<(KVH+255)/256, 256, 0, stream>>>(kv_g, kv_b, kv_m, kv_v, s_kv, b_kv, KVH);
    k_bn<<<(INDIM+255)/256, 256, 0, stream>>>(q_g, q_b, q_m, q_v, s_q, b_q, INDIM);
    k_bn<<<(OUTD+255)/256, 256, 0, stream>>>(pr_g, pr_b, pr_m, pr_v, s_pr, b_pr, OUTD);
    k_bias<<<(NH*NQ*NTOK+255)/256, 256, 0, stream>>>(ab, idxs, biasf, NH*NQ*NTOK, n_off);
    {
        int n = BSZ*NH*DV*(NPAD-NTOK);
        k_vtz<<<(n+255)/256, 256, 0, stream>>>(v_t, n);
    }

    // kv GEMM: (50176 x 1152 x 384)
    {
        dim3 g(BSZ*NTOK/128, KVH/128);
        k_gemm<0><<<g, 256, 0, stream>>>(x_bf, kvw_bf, s_kv, b_kv, k_bf, v_t, nullptr,
                                         BSZ*NTOK, KVH, INDIM);
    }
    // q GEMM: (12544 x 384 x 384)
    {
        dim3 g(BSZ*NQ/128, INDIM/128);
        k_gemm<1><<<g, 256, 0, stream>>>(xs_bf, qw_bf, s_q, b_q, q_out, nullptr, nullptr,
                                         BSZ*NQ, INDIM, INDIM);
    }
    // attention + hard_swish
    k_attn<<<BSZ*NH, 256, 0, stream>>>(q_out, k_bf, v_t, biasf, a_out);
    // proj GEMM: (12544 x 512 x 768) -> f32 out
    {
        dim3 g(BSZ*NQ/128, OUTD/128);
        k_gemm<2><<<g, 256, 0, stream>>>(a_out, prw_bf, s_pr, b_pr, nullptr, nullptr,
                                         (float*)d_out, BSZ*NQ, OUTD, DHD);
    }
}

// Round 2
// 287.290 us; speedup vs baseline: 1.0675x; 1.0675x over previous
//
#include <hip/hip_runtime.h>
#include <hip/hip_bf16.h>
#include <math.h>

typedef unsigned short U16;
typedef unsigned int U32;
typedef __attribute__((ext_vector_type(8))) short bf8;        // 8 x bf16 (MFMA A/B frag)
typedef __attribute__((ext_vector_type(4))) float f4;         // MFMA C/D frag
typedef __attribute__((ext_vector_type(4))) unsigned short u16x4;

#define AS1 __attribute__((address_space(1)))
#define AS3 __attribute__((address_space(3)))

// ---- constants ----
#define BSZ   256
#define NTOK  196
#define NQ    49
#define INDIM 384
#define OUTD  512
#define NH    12
#define HKD   32
#define DV    64
#define DHD   768
#define KVH   1152
#define NPAD  224      // PV K padded to 7*32
#define PST   232      // plds row stride (u16)

__device__ inline U16 f2bf(float f){
    __hip_bfloat16 h = __float2bfloat16(f);
    return *(U16*)&h;
}
__device__ inline f4 f4zero(){ f4 z; z[0]=0.f; z[1]=0.f; z[2]=0.f; z[3]=0.f; return z; }
__device__ inline bf8 bf8zero(){ bf8 v;
#pragma unroll
    for (int j=0;j<8;++j) v[j]=0; return v; }

// ---------------- prep kernels ----------------
__global__ void k_cast8(const float* __restrict__ in, U16* __restrict__ out, int n8){
    int i = blockIdx.x*256 + threadIdx.x;
    if (i >= n8) return;
    const float* p = in + (size_t)i*8;
    U16 o[8];
#pragma unroll
    for (int j=0;j<8;++j) o[j] = f2bf(p[j]);
    *(bf8*)(out + (size_t)i*8) = *(const bf8*)o;
}

__global__ void k_castxs(const float* __restrict__ x, U16* __restrict__ out, int n8){
    int i = blockIdx.x*256 + threadIdx.x;
    if (i >= n8) return;
    int row = i / 48;          // 48 = 384/8
    int c8  = i - row*48;
    int b   = row / 49;
    int q   = row - b*49;
    int r_  = q / 7, c_ = q - r_*7;
    const float* p = x + ((size_t)(b*NTOK + 28*r_ + 2*c_))*INDIM + c8*8;
    U16 o[8];
#pragma unroll
    for (int j=0;j<8;++j) o[j] = f2bf(p[j]);
    *(bf8*)(out + (size_t)i*8) = *(const bf8*)o;
}

// fold BN for all three linears in one launch: [0,1152) kv, [1152,1536) q, [1536,2048) proj
__global__ void k_bn3(const float* __restrict__ g1, const float* __restrict__ b1,
                      const float* __restrict__ m1, const float* __restrict__ v1,
                      const float* __restrict__ g2, const float* __restrict__ b2,
                      const float* __restrict__ m2, const float* __restrict__ v2,
                      const float* __restrict__ g3, const float* __restrict__ b3,
                      const float* __restrict__ m3, const float* __restrict__ v3,
                      float* __restrict__ s1, float* __restrict__ bo1,
                      float* __restrict__ s2, float* __restrict__ bo2,
                      float* __restrict__ s3, float* __restrict__ bo3){
    int i = blockIdx.x*256 + threadIdx.x;
    const float *g,*b,*m,*v; float *so,*bo; int k;
    if (i < KVH){ g=g1;b=b1;m=m1;v=v1;so=s1;bo=bo1;k=i; }
    else if (i < KVH+INDIM){ g=g2;b=b2;m=m2;v=v2;so=s2;bo=bo2;k=i-KVH; }
    else if (i < KVH+INDIM+OUTD){ g=g3;b=b3;m=m3;v=v3;so=s3;bo=bo3;k=i-KVH-INDIM; }
    else return;
    float s = g[k] / sqrtf(v[k] + 1e-5f);
    so[k] = s;
    bo[k] = b[k] - m[k]*s;
}

__global__ void k_bias(const float* __restrict__ ab, const int* __restrict__ idxs,
                       float* __restrict__ out, int n, int n_off){
    int i = blockIdx.x*256 + threadIdx.x;
    if (i >= n) return;
    int h = i / (NQ*NTOK);
    int qk = i - h*(NQ*NTOK);
    out[i] = ab[h*n_off + idxs[qk]];
}

__global__ void k_vtz(U16* __restrict__ vt, int n){   // zero v_t pad cols [196,224), u16x4
    int i = blockIdx.x*256 + threadIdx.x;
    if (i >= n) return;
    int bd = i / 7;
    int c  = i - bd*7;
    u16x4 z; z[0]=0; z[1]=0; z[2]=0; z[3]=0;
    *(u16x4*)(vt + (size_t)bd*NPAD + NTOK + c*4) = z;
}

// ---------------- 128x128x64 bf16 GEMM (B^T weights), chunk-major LDS ----------------
// LDS layout: [8 chunks of 16B][128 rows][8 u16] -> conflict-free ds_read_b128.
// EPI 0: kv split (k + v-transposed)   EPI 1: q bf16 store   EPI 2: proj f32 store
template<int EPI>
__global__ __launch_bounds__(256) void k_gemm(
    const U16* __restrict__ A, const U16* __restrict__ Bw,
    const float* __restrict__ s_arr, const float* __restrict__ b_arr,
    U16* __restrict__ o16a, U16* __restrict__ o16b, float* __restrict__ o32,
    int M, int N, int K)
{
    __shared__ U16 As[8*128*8];   // 16 KB
    __shared__ U16 Bs[8*128*8];   // 16 KB
    const int tid  = threadIdx.x;
    const int lane = tid & 63;
    const int w    = tid >> 6;
    const int wm   = w >> 1, wn = w & 1;
    const int l15  = lane & 15, oct = lane >> 4;
    const int gm0  = blockIdx.x * 128;
    const int gn0  = blockIdx.y * 128;

    f4 acc[4][4];
#pragma unroll
    for (int i=0;i<4;++i)
#pragma unroll
        for (int j=0;j<4;++j) acc[i][j] = f4zero();

    // staging: slot = w*256 + c*64 + lane; row = slot&127, chunk = slot>>7
    size_t aoff[4], boff[4];
#pragma unroll
    for (int c=0;c<4;++c){
        int slot = w*256 + c*64 + lane;
        int row = slot & 127, ch = slot >> 7;
        aoff[c] = (size_t)(gm0 + row)*K + ch*8;
        boff[c] = (size_t)(gn0 + row)*K + ch*8;
    }
    const int nk = K >> 6;

    for (int kt = 0; kt < nk; ++kt){
        const int kb = kt*64;
#pragma unroll
        for (int c=0;c<4;++c){
            __builtin_amdgcn_global_load_lds((const AS1 U32*)(A + aoff[c] + kb),
                (AS3 U32*)(As + (w*256 + c*64)*8), 16, 0, 0);
            __builtin_amdgcn_global_load_lds((const AS1 U32*)(Bw + boff[c] + kb),
                (AS3 U32*)(Bs + (w*256 + c*64)*8), 16, 0, 0);
        }
        __syncthreads();
#pragma unroll
        for (int kk=0;kk<2;++kk){
            bf8 af[4], bfr[4];
#pragma unroll
            for (int i=0;i<4;++i)
                af[i]  = *(const bf8*)(As + ((kk*4+oct)*128 + wm*64 + i*16 + l15)*8);
#pragma unroll
            for (int j=0;j<4;++j)
                bfr[j] = *(const bf8*)(Bs + ((kk*4+oct)*128 + wn*64 + j*16 + l15)*8);
#pragma unroll
            for (int i=0;i<4;++i)
#pragma unroll
                for (int j=0;j<4;++j)
                    acc[i][j] = __builtin_amdgcn_mfma_f32_16x16x32_bf16(af[i], bfr[j], acc[i][j], 0, 0, 0);
        }
        __syncthreads();
    }

    // epilogue: BN fold, then store per variant
#pragma unroll
    for (int j=0;j<4;++j){
        const int col = gn0 + wn*64 + j*16 + l15;
        const float sc = s_arr[col];
        const float bi = b_arr[col];
        const int h  = col / 96;
        const int rr = col - h*96;        // uniform k/v split per 16-col tile
#pragma unroll
        for (int i=0;i<4;++i){
            const int row0 = gm0 + wm*64 + i*16 + oct*4;
            if (EPI == 0){
                const int bb = row0 / NTOK;
                const int n0 = row0 - bb*NTOK;   // row0 % 4 == 0 and 196 % 4 == 0 -> same bb for r=0..3
                if (rr >= HKD){
                    U16* dst = o16b + ((size_t)(bb*NH + h)*DV + (rr - HKD))*NPAD + n0;
                    u16x4 pk;
#pragma unroll
                    for (int r=0;r<4;++r) pk[r] = f2bf(acc[i][j][r]*sc + bi);
                    *(u16x4*)dst = pk;
                } else {
                    U16* dst = o16a + ((size_t)(bb*NH + h)*NTOK + n0)*HKD + rr;
#pragma unroll
                    for (int r=0;r<4;++r) dst[(size_t)r*HKD] = f2bf(acc[i][j][r]*sc + bi);
                }
            } else if (EPI == 1){
#pragma unroll
                for (int r=0;r<4;++r)
                    o16a[(size_t)(row0+r)*INDIM + col] = f2bf(acc[i][j][r]*sc + bi);
            } else {
#pragma unroll
                for (int r=0;r<4;++r)
                    o32[(size_t)(row0+r)*OUTD + col] = acc[i][j][r]*sc + bi;
            }
        }
    }
}

// ---------------- fused attention: one block per (b,h), 4 waves x 16 q-cols ----------------
__global__ __launch_bounds__(256) void k_attn(
    const U16* __restrict__ qbf, const U16* __restrict__ kbf, const U16* __restrict__ vt,
    const float* __restrict__ bias_full, U16* __restrict__ aout)
{
    __shared__ U16 plds[64*PST];
    const int bh = blockIdx.x;
    const int b  = bh / NH, h = bh - b*NH;
    const int tid = threadIdx.x, lane = tid & 63, w = tid >> 6;
    const int l15 = lane & 15, oct = lane >> 4;

    // q fragment (B operand, col = l15): this lane's q index
    const int qg = w*16 + l15;
    bf8 qf = bf8zero();
    if (qg < NQ) qf = *(const bf8*)(qbf + ((size_t)(b*NQ + qg))*INDIM + h*HKD + oct*8);

    // QK^T swapped: C = attn^T tiles (rows = n, cols = q)
    f4 acc[13];
#pragma unroll
    for (int mt=0;mt<13;++mt) acc[mt] = f4zero();
#pragma unroll
    for (int mt=0;mt<13;++mt){
        int n = mt*16 + l15;
        bf8 kf = bf8zero();
        if (n < NTOK) kf = *(const bf8*)(kbf + ((size_t)bh*NTOK + n)*HKD + oct*8);
        acc[mt] = __builtin_amdgcn_mfma_f32_16x16x32_bf16(kf, qf, acc[mt], 0, 0, 0);
    }

    const float scale = 0.17677669529663689f;   // 1/sqrt(32)
    float mx = -1e30f;
#pragma unroll
    for (int mt=0;mt<13;++mt){
#pragma unroll
        for (int r=0;r<4;++r){
            int n = mt*16 + oct*4 + r;
            float s;
            if (n < NTOK){
                float bi = (qg < NQ) ? bias_full[((size_t)h*NQ + qg)*NTOK + n] : 0.f;
                s = acc[mt][r]*scale + bi;
            } else s = -1e30f;
            acc[mt][r] = s;
            mx = fmaxf(mx, s);
        }
    }
    mx = fmaxf(mx, __shfl_xor(mx, 16));
    mx = fmaxf(mx, __shfl_xor(mx, 32));

    float sum = 0.f;
#pragma unroll
    for (int mt=0;mt<13;++mt){
#pragma unroll
        for (int r=0;r<4;++r){
            int n = mt*16 + oct*4 + r;
            float p = (n < NTOK) ? __expf(acc[mt][r] - mx) : 0.f;
            acc[mt][r] = p;
            sum += p;
        }
    }
    sum += __shfl_xor(sum, 16);
    sum += __shfl_xor(sum, 32);
    const float inv = 1.f / sum;

    // write P (bf16) into LDS in PV A-fragment layout: row = q, cols n
    const int prow = w*16 + l15;
#pragma unroll
    for (int mt=0;mt<13;++mt){
        u16x4 pk;
#pragma unroll
        for (int r=0;r<4;++r) pk[r] = f2bf(acc[mt][r]*inv);
        *(u16x4*)(plds + prow*PST + mt*16 + oct*4) = pk;
    }
    if (oct == 0){
#pragma unroll
        for (int c=208;c<224;++c) plds[prow*PST + c] = 0;
    }
    __syncthreads();

    // PV: out(q,d) = P(q,n) @ v(n,d); A from LDS, B = v^T (b,h,d,n) from global
    f4 pacc[4];
#pragma unroll
    for (int dt=0;dt<4;++dt) pacc[dt] = f4zero();
#pragma unroll
    for (int kt=0;kt<7;++kt){
        bf8 pa = *(const bf8*)(plds + prow*PST + kt*32 + oct*8);
#pragma unroll
        for (int dt=0;dt<4;++dt){
            bf8 vf = *(const bf8*)(vt + ((size_t)bh*DV + dt*16 + l15)*NPAD + kt*32 + oct*8);
            pacc[dt] = __builtin_amdgcn_mfma_f32_16x16x32_bf16(pa, vf, pacc[dt], 0, 0, 0);
        }
    }

    // epilogue: hard_swish, store bf16 (b, q, h*64+d)
#pragma unroll
    for (int dt=0;dt<4;++dt){
#pragma unroll
        for (int r=0;r<4;++r){
            int qo = w*16 + oct*4 + r;
            if (qo < NQ){
                int d = dt*16 + l15;
                float v = pacc[dt][r];
                float t = fminf(fmaxf(v + 3.f, 0.f), 6.f);
                aout[((size_t)(b*NQ + qo))*DHD + h*DV + d] = f2bf(v * t * (1.f/6.f));
            }
        }
    }
}

// ---------------- launch ----------------
extern "C" void kernel_launch(void* const* d_in, const int* in_sizes, int n_in,
                              void* d_out, int out_size, void* d_ws, size_t ws_size,
                              hipStream_t stream)
{
    const float* x    = (const float*)d_in[0];
    const float* kv_w = (const float*)d_in[1];
    const float* kv_g = (const float*)d_in[2];
    const float* kv_b = (const float*)d_in[3];
    const float* kv_m = (const float*)d_in[4];
    const float* kv_v = (const float*)d_in[5];
    const float* q_w  = (const float*)d_in[6];
    const float* q_g  = (const float*)d_in[7];
    const float* q_b  = (const float*)d_in[8];
    const float* q_m  = (const float*)d_in[9];
    const float* q_v  = (const float*)d_in[10];
    const float* pr_w = (const float*)d_in[11];
    const float* pr_g = (const float*)d_in[12];
    const float* pr_b = (const float*)d_in[13];
    const float* pr_m = (const float*)d_in[14];
    const float* pr_v = (const float*)d_in[15];
    const float* ab   = (const float*)d_in[16];
    const int*  idxs  = (const int*)d_in[17];
    const int n_off = in_sizes[16] / NH;

    char* ws = (char*)d_ws;
    size_t off = 0;
    auto alloc = [&](size_t bytes)->char*{
        char* p = ws + off; off += (bytes + 255) & ~(size_t)255; return p;
    };
    U16*   x_bf   = (U16*)  alloc((size_t)BSZ*NTOK*INDIM*2);   // 38.5 MB
    U16*   xs_bf  = (U16*)  alloc((size_t)BSZ*NQ*INDIM*2);     // 9.6 MB
    U16*   kvw_bf = (U16*)  alloc((size_t)KVH*INDIM*2);
    U16*   qw_bf  = (U16*)  alloc((size_t)INDIM*INDIM*2);
    U16*   prw_bf = (U16*)  alloc((size_t)OUTD*DHD*2);
    float* s_kv   = (float*)alloc(KVH*4);
    float* b_kv   = (float*)alloc(KVH*4);
    float* s_q    = (float*)alloc(INDIM*4);
    float* b_q    = (float*)alloc(INDIM*4);
    float* s_pr   = (float*)alloc(OUTD*4);
    float* b_pr   = (float*)alloc(OUTD*4);
    float* biasf  = (float*)alloc((size_t)NH*NQ*NTOK*4);
    U16*   k_bf   = (U16*)  alloc((size_t)BSZ*NH*NTOK*HKD*2);  // 38.5 MB
    U16*   v_t    = (U16*)  alloc((size_t)BSZ*NH*DV*NPAD*2);   // 88 MB
    U16*   q_out  = (U16*)  alloc((size_t)BSZ*NQ*INDIM*2);     // 9.6 MB
    U16*   a_out  = (U16*)  alloc((size_t)BSZ*NQ*DHD*2);       // 19.3 MB
    if (off > ws_size) return;  // insufficient workspace: fail visibly (no OOB writes)

    // prep
    {
        int n8 = BSZ*NTOK*INDIM/8;
        k_cast8<<<(n8+255)/256, 256, 0, stream>>>(x, x_bf, n8);
    }
    {
        int n8 = BSZ*NQ*INDIM/8;
        k_castxs<<<(n8+255)/256, 256, 0, stream>>>(x, xs_bf, n8);
    }
    k_cast8<<<(KVH*INDIM/8+255)/256, 256, 0, stream>>>(kv_w, kvw_bf, KVH*INDIM/8);
    k_cast8<<<(INDIM*INDIM/8+255)/256, 256, 0, stream>>>(q_w, qw_bf, INDIM*INDIM/8);
    k_cast8<<<(OUTD*DHD/8+255)/256, 256, 0, stream>>>(pr_w, prw_bf, OUTD*DHD/8);
    k_bn3<<<(KVH+INDIM+OUTD+255)/256, 256, 0, stream>>>(
        kv_g, kv_b, kv_m, kv_v, q_g, q_b, q_m, q_v, pr_g, pr_b, pr_m, pr_v,
        s_kv, b_kv, s_q, b_q, s_pr, b_pr);
    k_bias<<<(NH*NQ*NTOK+255)/256, 256, 0, stream>>>(ab, idxs, biasf, NH*NQ*NTOK, n_off);
    {
        int n = BSZ*NH*DV*7;
        k_vtz<<<(n+255)/256, 256, 0, stream>>>(v_t, n);
    }

    // kv GEMM: (50176 x 1152 x 384)
    {
        dim3 g(BSZ*NTOK/128, KVH/128);
        k_gemm<0><<<g, 256, 0, stream>>>(x_bf, kvw_bf, s_kv, b_kv, k_bf, v_t, nullptr,
                                         BSZ*NTOK, KVH, INDIM);
    }
    // q GEMM: (12544 x 384 x 384)
    {
        dim3 g(BSZ*NQ/128, INDIM/128);
        k_gemm<1><<<g, 256, 0, stream>>>(xs_bf, qw_bf, s_q, b_q, q_out, nullptr, nullptr,
                                         BSZ*NQ, INDIM, INDIM);
    }
    // attention + hard_swish
    k_attn<<<BSZ*NH, 256, 0, stream>>>(q_out, k_bf, v_t, biasf, a_out);
    // proj GEMM: (12544 x 512 x 768) -> f32 out
    {
        dim3 g(BSZ*NQ/128, OUTD/128);
        k_gemm<2><<<g, 256, 0, stream>>>(a_out, prw_bf, s_pr, b_pr, nullptr, nullptr,
                                         (float*)d_out, BSZ*NQ, OUTD, DHD);
    }
}

// Round 3
// 268.324 us; speedup vs baseline: 1.1430x; 1.0707x over previous
//
#include <hip/hip_runtime.h>
#include <hip/hip_bf16.h>
#include <math.h>

typedef unsigned short U16;
typedef unsigned int U32;
typedef __attribute__((ext_vector_type(8))) short bf8;        // 8 x bf16 (MFMA A/B frag)
typedef __attribute__((ext_vector_type(4))) float f4;         // MFMA C/D frag
typedef __attribute__((ext_vector_type(4))) unsigned short u16x4;

#define AS1 __attribute__((address_space(1)))
#define AS3 __attribute__((address_space(3)))

// ---- constants ----
#define BSZ   256
#define NTOK  196
#define NQ    49
#define INDIM 384
#define OUTD  512
#define NH    12
#define HKD   32
#define DV    64
#define DHD   768
#define KVH   1152
#define NPAD  224      // PV K padded to 7*32
#define PST   232      // plds row stride (u16)

__device__ inline U16 f2bf(float f){
    __hip_bfloat16 h = __float2bfloat16(f);
    return *(U16*)&h;
}
__device__ inline f4 f4zero(){ f4 z; z[0]=0.f; z[1]=0.f; z[2]=0.f; z[3]=0.f; return z; }
__device__ inline bf8 bf8zero(){ bf8 v;
#pragma unroll
    for (int j=0;j<8;++j) v[j]=0; return v; }

// ---------------- prep kernels ----------------
__global__ void k_cast8(const float* __restrict__ in, U16* __restrict__ out, int n8){
    int i = blockIdx.x*256 + threadIdx.x;
    if (i >= n8) return;
    const float* p = in + (size_t)i*8;
    U16 o[8];
#pragma unroll
    for (int j=0;j<8;++j) o[j] = f2bf(p[j]);
    *(bf8*)(out + (size_t)i*8) = *(const bf8*)o;
}

__global__ void k_castxs(const float* __restrict__ x, U16* __restrict__ out, int n8){
    int i = blockIdx.x*256 + threadIdx.x;
    if (i >= n8) return;
    int row = i / 48;          // 48 = 384/8
    int c8  = i - row*48;
    int b   = row / 49;
    int q   = row - b*49;
    int r_  = q / 7, c_ = q - r_*7;
    const float* p = x + ((size_t)(b*NTOK + 28*r_ + 2*c_))*INDIM + c8*8;
    U16 o[8];
#pragma unroll
    for (int j=0;j<8;++j) o[j] = f2bf(p[j]);
    *(bf8*)(out + (size_t)i*8) = *(const bf8*)o;
}

// all three weight casts in one launch
#define W1C (KVH*INDIM/8)            // 55296
#define W2C (INDIM*INDIM/8)          // 18432
#define W3C (OUTD*DHD/8)             // 49152
__global__ void k_castw(const float* __restrict__ w1, const float* __restrict__ w2,
                        const float* __restrict__ w3, U16* __restrict__ o1,
                        U16* __restrict__ o2, U16* __restrict__ o3){
    int i = blockIdx.x*256 + threadIdx.x;
    const float* p; U16* o;
    if (i < W1C){ p = w1 + (size_t)i*8; o = o1 + (size_t)i*8; }
    else if (i < W1C+W2C){ int k=i-W1C; p = w2 + (size_t)k*8; o = o2 + (size_t)k*8; }
    else if (i < W1C+W2C+W3C){ int k=i-W1C-W2C; p = w3 + (size_t)k*8; o = o3 + (size_t)k*8; }
    else return;
    U16 t[8];
#pragma unroll
    for (int j=0;j<8;++j) t[j] = f2bf(p[j]);
    *(bf8*)o = *(const bf8*)t;
}

// bias expand + BN folds + v_t pad zero, one launch (block-range dispatch)
#define BIAS_N   (NH*NQ*NTOK)        // 115248
#define BIAS_BLK ((BIAS_N+255)/256)  // 451
#define BN_N     (KVH+INDIM+OUTD)    // 2048
#define BN_BLK   (BN_N/256)          // 8
#define VTZ_N    (BSZ*NH*DV*7)       // quads
#define VTZ_BLK  (VTZ_N/256)         // 5376
__global__ void k_misc(const float* __restrict__ ab, const int* __restrict__ idxs, int n_off,
                       const float* __restrict__ g1, const float* __restrict__ b1,
                       const float* __restrict__ m1, const float* __restrict__ v1,
                       const float* __restrict__ g2, const float* __restrict__ b2,
                       const float* __restrict__ m2, const float* __restrict__ v2,
                       const float* __restrict__ g3, const float* __restrict__ b3,
                       const float* __restrict__ m3, const float* __restrict__ v3,
                       float* __restrict__ s1, float* __restrict__ bo1,
                       float* __restrict__ s2, float* __restrict__ bo2,
                       float* __restrict__ s3, float* __restrict__ bo3,
                       float* __restrict__ bias_out, U16* __restrict__ vt){
    int blk = blockIdx.x;
    int tid = threadIdx.x;
    if (blk < BIAS_BLK){
        int i = blk*256 + tid;
        if (i < BIAS_N){
            int h = i / (NQ*NTOK);
            int qk = i - h*(NQ*NTOK);
            bias_out[i] = ab[h*n_off + idxs[qk]];
        }
    } else if (blk < BIAS_BLK + BN_BLK){
        int i = (blk-BIAS_BLK)*256 + tid;
        const float *g,*b,*m,*v; float *so,*bo; int k;
        if (i < KVH){ g=g1;b=b1;m=m1;v=v1;so=s1;bo=bo1;k=i; }
        else if (i < KVH+INDIM){ g=g2;b=b2;m=m2;v=v2;so=s2;bo=bo2;k=i-KVH; }
        else { g=g3;b=b3;m=m3;v=v3;so=s3;bo=bo3;k=i-KVH-INDIM; }
        float s = g[k] / sqrtf(v[k] + 1e-5f);
        so[k] = s;
        bo[k] = b[k] - m[k]*s;
    } else {
        int i = (blk-BIAS_BLK-BN_BLK)*256 + tid;   // quad index
        int bd = i / 7;
        int c  = i - bd*7;
        u16x4 z; z[0]=0; z[1]=0; z[2]=0; z[3]=0;
        *(u16x4*)(vt + (size_t)bd*NPAD + NTOK + c*4) = z;
    }
}

// ---------------- 128x128x64 bf16 GEMM, double-buffered 2-phase pipeline ----------------
// LDS: chunk-major [8 chunks of 16B][128 rows][8 u16] per buffer -> conflict-free ds_read_b128.
// Per K-step: STAGE(next) -> ds_read(cur)+MFMA -> one __syncthreads() (vmcnt+lgkm drain).
// EPI 0: kv split (k + v-transposed)   EPI 1: q bf16 store   EPI 2: proj f32 store
template<int EPI, int NK>
__global__ __launch_bounds__(256) void k_gemm(
    const U16* __restrict__ A, const U16* __restrict__ Bw,
    const float* __restrict__ s_arr, const float* __restrict__ b_arr,
    U16* __restrict__ o16a, U16* __restrict__ o16b, float* __restrict__ o32,
    int M, int N, int K)
{
    __shared__ U16 As[2][8*128*8];   // 2 x 16 KB
    __shared__ U16 Bs[2][8*128*8];   // 2 x 16 KB
    const int tid  = threadIdx.x;
    const int lane = tid & 63;
    const int w    = tid >> 6;
    const int wm   = w >> 1, wn = w & 1;
    const int l15  = lane & 15, oct = lane >> 4;
    const int gm0  = blockIdx.x * 128;
    const int gn0  = blockIdx.y * 128;

    f4 acc[4][4];
#pragma unroll
    for (int i=0;i<4;++i)
#pragma unroll
        for (int j=0;j<4;++j) acc[i][j] = f4zero();

    // staging: slot = w*256 + c*64 + lane; row = slot&127, chunk = slot>>7
    size_t aoff[4], boff[4];
#pragma unroll
    for (int c=0;c<4;++c){
        int slot = w*256 + c*64 + lane;
        int row = slot & 127, ch = slot >> 7;
        aoff[c] = (size_t)(gm0 + row)*K + ch*8;
        boff[c] = (size_t)(gn0 + row)*K + ch*8;
    }

    // prologue: stage tile 0 into buf 0
#pragma unroll
    for (int c=0;c<4;++c){
        __builtin_amdgcn_global_load_lds((const AS1 U32*)(A + aoff[c]),
            (AS3 U32*)(&As[0][(w*256 + c*64)*8]), 16, 0, 0);
        __builtin_amdgcn_global_load_lds((const AS1 U32*)(Bw + boff[c]),
            (AS3 U32*)(&Bs[0][(w*256 + c*64)*8]), 16, 0, 0);
    }
    __syncthreads();

#pragma unroll
    for (int kt = 0; kt < NK; ++kt){
        const int buf = kt & 1;
        // issue next-tile staging first (overlaps with this tile's compute)
        if (kt+1 < NK){
            const int kb = (kt+1)*64;
#pragma unroll
            for (int c=0;c<4;++c){
                __builtin_amdgcn_global_load_lds((const AS1 U32*)(A + aoff[c] + kb),
                    (AS3 U32*)(&As[buf^1][(w*256 + c*64)*8]), 16, 0, 0);
                __builtin_amdgcn_global_load_lds((const AS1 U32*)(Bw + boff[c] + kb),
                    (AS3 U32*)(&Bs[buf^1][(w*256 + c*64)*8]), 16, 0, 0);
            }
        }
#pragma unroll
        for (int kk=0;kk<2;++kk){
            bf8 af[4], bfr[4];
#pragma unroll
            for (int i=0;i<4;++i)
                af[i]  = *(const bf8*)(&As[buf][((kk*4+oct)*128 + wm*64 + i*16 + l15)*8]);
#pragma unroll
            for (int j=0;j<4;++j)
                bfr[j] = *(const bf8*)(&Bs[buf][((kk*4+oct)*128 + wn*64 + j*16 + l15)*8]);
#pragma unroll
            for (int i=0;i<4;++i)
#pragma unroll
                for (int j=0;j<4;++j)
                    acc[i][j] = __builtin_amdgcn_mfma_f32_16x16x32_bf16(af[i], bfr[j], acc[i][j], 0, 0, 0);
        }
        __syncthreads();   // drains vmcnt(0)+lgkmcnt(0): next buffer ready, cur buffer free
    }

    // epilogue: BN fold, then store per variant
#pragma unroll
    for (int j=0;j<4;++j){
        const int col = gn0 + wn*64 + j*16 + l15;
        const float sc = s_arr[col];
        const float bi = b_arr[col];
        const int h  = col / 96;
        const int rr = col - h*96;        // uniform k/v split per 16-col tile
#pragma unroll
        for (int i=0;i<4;++i){
            const int row0 = gm0 + wm*64 + i*16 + oct*4;
            if (EPI == 0){
                const int bb = row0 / NTOK;
                const int n0 = row0 - bb*NTOK;   // row0%4==0, 196%4==0 -> same bb for r=0..3
                if (rr >= HKD){
                    U16* dst = o16b + ((size_t)(bb*NH + h)*DV + (rr - HKD))*NPAD + n0;
                    u16x4 pk;
#pragma unroll
                    for (int r=0;r<4;++r) pk[r] = f2bf(acc[i][j][r]*sc + bi);
                    *(u16x4*)dst = pk;
                } else {
                    U16* dst = o16a + ((size_t)(bb*NH + h)*NTOK + n0)*HKD + rr;
#pragma unroll
                    for (int r=0;r<4;++r) dst[(size_t)r*HKD] = f2bf(acc[i][j][r]*sc + bi);
                }
            } else if (EPI == 1){
#pragma unroll
                for (int r=0;r<4;++r)
                    o16a[(size_t)(row0+r)*INDIM + col] = f2bf(acc[i][j][r]*sc + bi);
            } else {
#pragma unroll
                for (int r=0;r<4;++r)
                    o32[(size_t)(row0+r)*OUTD + col] = acc[i][j][r]*sc + bi;
            }
        }
    }
}

// ---------------- fused attention: one block per (b,h), 4 waves x 16 q-cols ----------------
// v-tile (64x224 bf16 = 28 KB) staged once into LDS at kernel start (global_load_lds),
// drained by the pre-PV __syncthreads(); hides under QK^T + softmax.
__global__ __launch_bounds__(256) void k_attn(
    const U16* __restrict__ qbf, const U16* __restrict__ kbf, const U16* __restrict__ vt,
    const float* __restrict__ bias_full, U16* __restrict__ aout)
{
    __shared__ U16 plds[64*PST];      // 29696 B
    __shared__ U16 vlds[28*64*8];     // 28672 B, chunk-major [ch][row][8]
    const int bh = blockIdx.x;
    const int b  = bh / NH, h = bh - b*NH;
    const int tid = threadIdx.x, lane = tid & 63, w = tid >> 6;
    const int l15 = lane & 15, oct = lane >> 4;

    // stage v: 7 rounds x 256 threads x 16B; per wave: ch = r*4+w fixed, row = lane
    {
        const U16* vsrc = vt + (size_t)bh*DV*NPAD;
#pragma unroll
        for (int r=0;r<7;++r){
            int slot = r*256 + tid;
            __builtin_amdgcn_global_load_lds((const AS1 U32*)(vsrc + (size_t)(slot & 63)*NPAD + (slot >> 6)*8),
                (AS3 U32*)(vlds + (size_t)(r*256 + w*64)*8), 16, 0, 0);
        }
    }

    // q fragment (B operand, col = l15): this lane's q index
    const int qg = w*16 + l15;
    bf8 qf = bf8zero();
    if (qg < NQ) qf = *(const bf8*)(qbf + ((size_t)(b*NQ + qg))*INDIM + h*HKD + oct*8);

    // QK^T swapped: C = attn^T tiles (rows = n, cols = q)
    f4 acc[13];
#pragma unroll
    for (int mt=0;mt<13;++mt) acc[mt] = f4zero();
#pragma unroll
    for (int mt=0;mt<13;++mt){
        int n = mt*16 + l15;
        bf8 kf = bf8zero();
        if (n < NTOK) kf = *(const bf8*)(kbf + ((size_t)bh*NTOK + n)*HKD + oct*8);
        acc[mt] = __builtin_amdgcn_mfma_f32_16x16x32_bf16(kf, qf, acc[mt], 0, 0, 0);
    }

    const float scale = 0.17677669529663689f;   // 1/sqrt(32)
    float mx = -1e30f;
#pragma unroll
    for (int mt=0;mt<13;++mt){
        f4 bi4 = f4zero();
        if (qg < NQ) bi4 = *(const f4*)(bias_full + ((size_t)h*NQ + qg)*NTOK + mt*16 + oct*4);
#pragma unroll
        for (int r=0;r<4;++r){
            int n = mt*16 + oct*4 + r;
            float s = (n < NTOK) ? acc[mt][r]*scale + bi4[r] : -1e30f;
            acc[mt][r] = s;
            mx = fmaxf(mx, s);
        }
    }
    mx = fmaxf(mx, __shfl_xor(mx, 16));
    mx = fmaxf(mx, __shfl_xor(mx, 32));

    float sum = 0.f;
#pragma unroll
    for (int mt=0;mt<13;++mt){
#pragma unroll
        for (int r=0;r<4;++r){
            int n = mt*16 + oct*4 + r;
            float p = (n < NTOK) ? __expf(acc[mt][r] - mx) : 0.f;
            acc[mt][r] = p;
            sum += p;
        }
    }
    sum += __shfl_xor(sum, 16);
    sum += __shfl_xor(sum, 32);
    const float inv = 1.f / sum;

    // write P (bf16) into LDS in PV A-fragment layout: row = q, cols n
    const int prow = w*16 + l15;
#pragma unroll
    for (int mt=0;mt<13;++mt){
        u16x4 pk;
#pragma unroll
        for (int r=0;r<4;++r) pk[r] = f2bf(acc[mt][r]*inv);
        *(u16x4*)(plds + prow*PST + mt*16 + oct*4) = pk;
    }
    if (oct == 0){
#pragma unroll
        for (int c=208;c<224;++c) plds[prow*PST + c] = 0;
    }
    __syncthreads();   // drains vmcnt(0) too -> vlds ready

    // PV: out(q,d) = P(q,n) @ v(n,d); A from LDS, B = v^T from LDS (chunk-major)
    f4 pacc[4];
#pragma unroll
    for (int dt=0;dt<4;++dt) pacc[dt] = f4zero();
#pragma unroll
    for (int kt=0;kt<7;++kt){
        bf8 pa = *(const bf8*)(plds + prow*PST + kt*32 + oct*8);
#pragma unroll
        for (int dt=0;dt<4;++dt){
            bf8 vf = *(const bf8*)(vlds + (size_t)((kt*4+oct)*64 + dt*16 + l15)*8);
            pacc[dt] = __builtin_amdgcn_mfma_f32_16x16x32_bf16(pa, vf, pacc[dt], 0, 0, 0);
        }
    }

    // epilogue: hard_swish, store bf16 (b, q, h*64+d)
#pragma unroll
    for (int dt=0;dt<4;++dt){
#pragma unroll
        for (int r=0;r<4;++r){
            int qo = w*16 + oct*4 + r;
            if (qo < NQ){
                int d = dt*16 + l15;
                float v = pacc[dt][r];
                float t = fminf(fmaxf(v + 3.f, 0.f), 6.f);
                aout[((size_t)(b*NQ + qo))*DHD + h*DV + d] = f2bf(v * t * (1.f/6.f));
            }
        }
    }
}

// ---------------- launch ----------------
extern "C" void kernel_launch(void* const* d_in, const int* in_sizes, int n_in,
                              void* d_out, int out_size, void* d_ws, size_t ws_size,
                              hipStream_t stream)
{
    const float* x    = (const float*)d_in[0];
    const float* kv_w = (const float*)d_in[1];
    const float* kv_g = (const float*)d_in[2];
    const float* kv_b = (const float*)d_in[3];
    const float* kv_m = (const float*)d_in[4];
    const float* kv_v = (const float*)d_in[5];
    const float* q_w  = (const float*)d_in[6];
    const float* q_g  = (const float*)d_in[7];
    const float* q_b  = (const float*)d_in[8];
    const float* q_m  = (const float*)d_in[9];
    const float* q_v  = (const float*)d_in[10];
    const float* pr_w = (const float*)d_in[11];
    const float* pr_g = (const float*)d_in[12];
    const float* pr_b = (const float*)d_in[13];
    const float* pr_m = (const float*)d_in[14];
    const float* pr_v = (const float*)d_in[15];
    const float* ab   = (const float*)d_in[16];
    const int*  idxs  = (const int*)d_in[17];
    const int n_off = in_sizes[16] / NH;

    char* ws = (char*)d_ws;
    size_t off = 0;
    auto alloc = [&](size_t bytes)->char*{
        char* p = ws + off; off += (bytes + 255) & ~(size_t)255; return p;
    };
    U16*   x_bf   = (U16*)  alloc((size_t)BSZ*NTOK*INDIM*2);   // 38.5 MB
    U16*   xs_bf  = (U16*)  alloc((size_t)BSZ*NQ*INDIM*2);     // 9.6 MB
    U16*   kvw_bf = (U16*)  alloc((size_t)KVH*INDIM*2);
    U16*   qw_bf  = (U16*)  alloc((size_t)INDIM*INDIM*2);
    U16*   prw_bf = (U16*)  alloc((size_t)OUTD*DHD*2);
    float* s_kv   = (float*)alloc(KVH*4);
    float* b_kv   = (float*)alloc(KVH*4);
    float* s_q    = (float*)alloc(INDIM*4);
    float* b_q    = (float*)alloc(INDIM*4);
    float* s_pr   = (float*)alloc(OUTD*4);
    float* b_pr   = (float*)alloc(OUTD*4);
    float* biasf  = (float*)alloc(((size_t)NH*NQ*NTOK + 256)*4);  // +pad for f4 tail reads
    U16*   k_bf   = (U16*)  alloc((size_t)BSZ*NH*NTOK*HKD*2);  // 38.5 MB
    U16*   v_t    = (U16*)  alloc((size_t)BSZ*NH*DV*NPAD*2);   // 88 MB
    U16*   q_out  = (U16*)  alloc((size_t)BSZ*NQ*INDIM*2);     // 9.6 MB
    U16*   a_out  = (U16*)  alloc((size_t)BSZ*NQ*DHD*2);       // 19.3 MB
    if (off > ws_size) return;  // insufficient workspace: fail visibly (no OOB writes)

    // prep (4 launches)
    {
        int n8 = BSZ*NTOK*INDIM/8;
        k_cast8<<<(n8+255)/256, 256, 0, stream>>>(x, x_bf, n8);
    }
    {
        int n8 = BSZ*NQ*INDIM/8;
        k_castxs<<<(n8+255)/256, 256, 0, stream>>>(x, xs_bf, n8);
    }
    k_castw<<<(W1C+W2C+W3C+255)/256, 256, 0, stream>>>(kv_w, q_w, pr_w, kvw_bf, qw_bf, prw_bf);
    k_misc<<<BIAS_BLK+BN_BLK+VTZ_BLK, 256, 0, stream>>>(
        ab, idxs, n_off,
        kv_g, kv_b, kv_m, kv_v, q_g, q_b, q_m, q_v, pr_g, pr_b, pr_m, pr_v,
        s_kv, b_kv, s_q, b_q, s_pr, b_pr, biasf, v_t);

    // kv GEMM: (50176 x 1152 x 384)
    {
        dim3 g(BSZ*NTOK/128, KVH/128);
        k_gemm<0, INDIM/64><<<g, 256, 0, stream>>>(x_bf, kvw_bf, s_kv, b_kv, k_bf, v_t, nullptr,
                                                   BSZ*NTOK, KVH, INDIM);
    }
    // q GEMM: (12544 x 384 x 384)
    {
        dim3 g(BSZ*NQ/128, INDIM/128);
        k_gemm<1, INDIM/64><<<g, 256, 0, stream>>>(xs_bf, qw_bf, s_q, b_q, q_out, nullptr, nullptr,
                                                   BSZ*NQ, INDIM, INDIM);
    }
    // attention + hard_swish
    k_attn<<<BSZ*NH, 256, 0, stream>>>(q_out, k_bf, v_t, biasf, a_out);
    // proj GEMM: (12544 x 512 x 768) -> f32 out
    {
        dim3 g(BSZ*NQ/128, OUTD/128);
        k_gemm<2, DHD/64><<<g, 256, 0, stream>>>(a_out, prw_bf, s_pr, b_pr, nullptr, nullptr,
                                                 (float*)d_out, BSZ*NQ, OUTD, DHD);
    }
}

// Round 4
// 247.501 us; speedup vs baseline: 1.2391x; 1.0841x over previous
//
#include <hip/hip_runtime.h>
#include <hip/hip_bf16.h>
#include <math.h>

typedef unsigned short U16;
typedef unsigned int U32;
typedef __attribute__((ext_vector_type(8))) short bf8;        // 8 x bf16 (MFMA A/B frag)
typedef __attribute__((ext_vector_type(4))) float f4;         // MFMA C/D frag
typedef __attribute__((ext_vector_type(4))) unsigned short u16x4;

#define AS1 __attribute__((address_space(1)))
#define AS3 __attribute__((address_space(3)))

// ---- constants ----
#define BSZ   256
#define NTOK  196
#define NQ    49
#define INDIM 384
#define OUTD  512
#define NH    12
#define HKD   32
#define DV    64
#define DHD   768
#define KVH   1152
#define NPAD  224      // PV K padded to 7*32
#define PST   232      // plds row stride (u16)
#define CST   132      // clds row stride (u16): 264B, 8B-aligned rows, odd-ish bank walk

__device__ inline U16 f2bf(float f){
    __hip_bfloat16 h = __float2bfloat16(f);
    return *(U16*)&h;
}
__device__ inline f4 f4zero(){ f4 z; z[0]=0.f; z[1]=0.f; z[2]=0.f; z[3]=0.f; return z; }
__device__ inline bf8 bf8zero(){ bf8 v;
#pragma unroll
    for (int j=0;j<8;++j) v[j]=0; return v; }

// ---------------- prep kernels ----------------
__global__ void k_cast8(const float* __restrict__ in, U16* __restrict__ out, int n8){
    int i = blockIdx.x*256 + threadIdx.x;
    if (i >= n8) return;
    const float* p = in + (size_t)i*8;
    U16 o[8];
#pragma unroll
    for (int j=0;j<8;++j) o[j] = f2bf(p[j]);
    *(bf8*)(out + (size_t)i*8) = *(const bf8*)o;
}

__global__ void k_castxs(const float* __restrict__ x, U16* __restrict__ out, int n8){
    int i = blockIdx.x*256 + threadIdx.x;
    if (i >= n8) return;
    int row = i / 48;          // 48 = 384/8
    int c8  = i - row*48;
    int b   = row / 49;
    int q   = row - b*49;
    int r_  = q / 7, c_ = q - r_*7;
    const float* p = x + ((size_t)(b*NTOK + 28*r_ + 2*c_))*INDIM + c8*8;
    U16 o[8];
#pragma unroll
    for (int j=0;j<8;++j) o[j] = f2bf(p[j]);
    *(bf8*)(out + (size_t)i*8) = *(const bf8*)o;
}

// all three weight casts in one launch
#define W1C (KVH*INDIM/8)            // 55296
#define W2C (INDIM*INDIM/8)          // 18432
#define W3C (OUTD*DHD/8)             // 49152
__global__ void k_castw(const float* __restrict__ w1, const float* __restrict__ w2,
                        const float* __restrict__ w3, U16* __restrict__ o1,
                        U16* __restrict__ o2, U16* __restrict__ o3){
    int i = blockIdx.x*256 + threadIdx.x;
    const float* p; U16* o;
    if (i < W1C){ p = w1 + (size_t)i*8; o = o1 + (size_t)i*8; }
    else if (i < W1C+W2C){ int k=i-W1C; p = w2 + (size_t)k*8; o = o2 + (size_t)k*8; }
    else if (i < W1C+W2C+W3C){ int k=i-W1C-W2C; p = w3 + (size_t)k*8; o = o3 + (size_t)k*8; }
    else return;
    U16 t[8];
#pragma unroll
    for (int j=0;j<8;++j) t[j] = f2bf(p[j]);
    *(bf8*)o = *(const bf8*)t;
}

// bias expand + BN folds + v_t pad zero, one launch (block-range dispatch)
#define BIAS_N   (NH*NQ*NTOK)        // 115248
#define BIAS_BLK ((BIAS_N+255)/256)  // 451
#define BN_N     (KVH+INDIM+OUTD)    // 2048
#define BN_BLK   (BN_N/256)          // 8
#define VTZ_N    (BSZ*NH*DV*7)       // quads
#define VTZ_BLK  (VTZ_N/256)         // 5376
__global__ void k_misc(const float* __restrict__ ab, const int* __restrict__ idxs, int n_off,
                       const float* __restrict__ g1, const float* __restrict__ b1,
                       const float* __restrict__ m1, const float* __restrict__ v1,
                       const float* __restrict__ g2, const float* __restrict__ b2,
                       const float* __restrict__ m2, const float* __restrict__ v2,
                       const float* __restrict__ g3, const float* __restrict__ b3,
                       const float* __restrict__ m3, const float* __restrict__ v3,
                       float* __restrict__ s1, float* __restrict__ bo1,
                       float* __restrict__ s2, float* __restrict__ bo2,
                       float* __restrict__ s3, float* __restrict__ bo3,
                       float* __restrict__ bias_out, U16* __restrict__ vt){
    int blk = blockIdx.x;
    int tid = threadIdx.x;
    if (blk < BIAS_BLK){
        int i = blk*256 + tid;
        if (i < BIAS_N){
            int h = i / (NQ*NTOK);
            int qk = i - h*(NQ*NTOK);
            bias_out[i] = ab[h*n_off + idxs[qk]];
        }
    } else if (blk < BIAS_BLK + BN_BLK){
        int i = (blk-BIAS_BLK)*256 + tid;
        const float *g,*b,*m,*v; float *so,*bo; int k;
        if (i < KVH){ g=g1;b=b1;m=m1;v=v1;so=s1;bo=bo1;k=i; }
        else if (i < KVH+INDIM){ g=g2;b=b2;m=m2;v=v2;so=s2;bo=bo2;k=i-KVH; }
        else { g=g3;b=b3;m=m3;v=v3;so=s3;bo=bo3;k=i-KVH-INDIM; }
        float s = g[k] / sqrtf(v[k] + 1e-5f);
        so[k] = s;
        bo[k] = b[k] - m[k]*s;
    } else {
        int i = (blk-BIAS_BLK-BN_BLK)*256 + tid;   // quad index
        int bd = i / 7;
        int c  = i - bd*7;
        u16x4 z; z[0]=0; z[1]=0; z[2]=0; z[3]=0;
        *(u16x4*)(vt + (size_t)bd*NPAD + NTOK + c*4) = z;
    }
}

// ---------------- 128x128x64 bf16 GEMM, double-buffered, LDS-transpose kv epilogue ----
// LDS staging: chunk-major [8 chunks of 16B][128 rows][8 u16] per buffer, conflict-free.
// Grid: blockIdx.x = N-tile (few), blockIdx.y = M-tile (many) -> A-panel reuse is temporal.
// EPI 0: kv split via clds transpose   EPI 1: q bf16 direct   EPI 2: proj f32 direct
template<int EPI, int NK>
__global__ __launch_bounds__(256) void k_gemm(
    const U16* __restrict__ A, const U16* __restrict__ Bw,
    const float* __restrict__ s_arr, const float* __restrict__ b_arr,
    U16* __restrict__ o16a, U16* __restrict__ o16b, float* __restrict__ o32,
    int M, int N, int K)
{
    __shared__ U16 smem[32768];   // 64 KB: [0,16K)=A0 [16K,32K)=A1 | [32K,48K)=B0 [48K,64K)=B1 (u16 idx)
    U16* Abuf[2] = { smem,          smem + 8192 };
    U16* Bbuf[2] = { smem + 16384,  smem + 24576 };
    const int tid  = threadIdx.x;
    const int lane = tid & 63;
    const int w    = tid >> 6;
    const int wm   = w >> 1, wn = w & 1;
    const int l15  = lane & 15, oct = lane >> 4;
    const int gn0  = blockIdx.x * 128;
    const int gm0  = blockIdx.y * 128;

    f4 acc[4][4];
#pragma unroll
    for (int i=0;i<4;++i)
#pragma unroll
        for (int j=0;j<4;++j) acc[i][j] = f4zero();

    // staging: slot = w*256 + c*64 + lane; row = slot&127, chunk = slot>>7
    size_t aoff[4], boff[4];
#pragma unroll
    for (int c=0;c<4;++c){
        int slot = w*256 + c*64 + lane;
        int row = slot & 127, ch = slot >> 7;
        aoff[c] = (size_t)(gm0 + row)*K + ch*8;
        boff[c] = (size_t)(gn0 + row)*K + ch*8;
    }

    // prologue: stage tile 0 into buf 0
#pragma unroll
    for (int c=0;c<4;++c){
        __builtin_amdgcn_global_load_lds((const AS1 U32*)(A + aoff[c]),
            (AS3 U32*)(Abuf[0] + (w*256 + c*64)*8), 16, 0, 0);
        __builtin_amdgcn_global_load_lds((const AS1 U32*)(Bw + boff[c]),
            (AS3 U32*)(Bbuf[0] + (w*256 + c*64)*8), 16, 0, 0);
    }
    __syncthreads();

#pragma unroll
    for (int kt = 0; kt < NK; ++kt){
        const int buf = kt & 1;
        // issue next-tile staging first (overlaps with this tile's compute)
        if (kt+1 < NK){
            const int kb = (kt+1)*64;
#pragma unroll
            for (int c=0;c<4;++c){
                __builtin_amdgcn_global_load_lds((const AS1 U32*)(A + aoff[c] + kb),
                    (AS3 U32*)(Abuf[buf^1] + (w*256 + c*64)*8), 16, 0, 0);
                __builtin_amdgcn_global_load_lds((const AS1 U32*)(Bw + boff[c] + kb),
                    (AS3 U32*)(Bbuf[buf^1] + (w*256 + c*64)*8), 16, 0, 0);
            }
        }
#pragma unroll
        for (int kk=0;kk<2;++kk){
            bf8 af[4], bfr[4];
#pragma unroll
            for (int i=0;i<4;++i)
                af[i]  = *(const bf8*)(Abuf[buf] + ((kk*4+oct)*128 + wm*64 + i*16 + l15)*8);
#pragma unroll
            for (int j=0;j<4;++j)
                bfr[j] = *(const bf8*)(Bbuf[buf] + ((kk*4+oct)*128 + wn*64 + j*16 + l15)*8);
#pragma unroll
            for (int i=0;i<4;++i)
#pragma unroll
                for (int j=0;j<4;++j)
                    acc[i][j] = __builtin_amdgcn_mfma_f32_16x16x32_bf16(af[i], bfr[j], acc[i][j], 0, 0, 0);
        }
        __syncthreads();   // drains vmcnt+lgkm: next buffer ready, cur buffer free
    }

    if (EPI == 0){
        // ---- transpose epilogue: acc -> clds_t [col][CST] (bf16, BN applied) ----
        U16* clds = smem;   // aliases staging buffers; dead after final barrier
#pragma unroll
        for (int j=0;j<4;++j){
            const int c = wn*64 + j*16 + l15;
            const float sc = s_arr[gn0 + c];
            const float bi = b_arr[gn0 + c];
#pragma unroll
            for (int i=0;i<4;++i){
                const int r0 = wm*64 + i*16 + oct*4;
                u16x4 pk;
#pragma unroll
                for (int r=0;r<4;++r) pk[r] = f2bf(acc[i][j][r]*sc + bi);
                *(u16x4*)(clds + c*CST + r0) = pk;   // r contiguous -> b64 write
            }
        }
        __syncthreads();

        const int m0 = gn0 % 96;
        int sA, lA, sB, cpr, kshift;       // k-col segments, chunks-per-row
        int vA_s, vA_l, vB_s, vcols;       // v-col segments
        if (m0 == 0){ sA=0; lA=32; sB=96; cpr=16; kshift=4; vA_s=32; vA_l=64; vB_s=0; vcols=64; }
        else if (m0 == 32){ sA=64; lA=32; sB=0; cpr=8; kshift=3; vA_s=0; vA_l=64; vB_s=96; vcols=96; }
        else { sA=32; lA=32; sB=0; cpr=8; kshift=3; vA_s=0; vA_l=32; vB_s=64; vcols=96; }

        // k-part: chunk = (row n, 4 consecutive rr); adjacent lanes -> adjacent rr chunks
        for (int t = tid; t < 128*cpr; t += 256){
            int kc4 = (t & (cpr-1))*4;
            int rowl = t >> kshift;
            int c0 = (kc4 < lA) ? sA + kc4 : sB + (kc4 - lA);
            int g = gn0 + c0, hh = g/96, rr = g - hh*96;
            int n = gm0 + rowl, bb2 = n/NTOK, nn = n - bb2*NTOK;
            u16x4 val;
#pragma unroll
            for (int j2=0;j2<4;++j2) val[j2] = clds[(c0+j2)*CST + rowl];
            *(u16x4*)(o16a + ((size_t)(bb2*NH+hh)*NTOK + nn)*HKD + rr) = val;
        }
        // v-part: chunk = (col d, 4 consecutive n); 32 adjacent lanes -> 256B contiguous
        for (int t = tid; t < vcols*32; t += 256){
            int vi = t >> 5, nc = t & 31;
            int c = (vi < vA_l) ? vA_s + vi : vB_s + (vi - vA_l);
            int g = gn0 + c, hh = g/96, rr = g - hh*96;   // rr in [32,96)
            int n0 = gm0 + nc*4, bb2 = n0/NTOK, nn = n0 - bb2*NTOK;
            u16x4 val = *(const u16x4*)(clds + c*CST + nc*4);
            *(u16x4*)(o16b + ((size_t)(bb2*NH+hh)*DV + (rr-HKD))*NPAD + nn) = val;
        }
    } else {
        // direct epilogues (q bf16 / proj f32)
#pragma unroll
        for (int j=0;j<4;++j){
            const int col = gn0 + wn*64 + j*16 + l15;
            const float sc = s_arr[col];
            const float bi = b_arr[col];
#pragma unroll
            for (int i=0;i<4;++i){
                const int row0 = gm0 + wm*64 + i*16 + oct*4;
                if (EPI == 1){
#pragma unroll
                    for (int r=0;r<4;++r)
                        o16a[(size_t)(row0+r)*INDIM + col] = f2bf(acc[i][j][r]*sc + bi);
                } else {
#pragma unroll
                    for (int r=0;r<4;++r)
                        o32[(size_t)(row0+r)*OUTD + col] = acc[i][j][r]*sc + bi;
                }
            }
        }
    }
}

// ---------------- fused attention: one block per (b,h), 4 waves x 16 q-cols ----------------
// v-tile (64x224 bf16 = 28 KB) staged once into LDS at kernel start (global_load_lds),
// drained by the pre-PV __syncthreads(); hides under QK^T + softmax.
__global__ __launch_bounds__(256) void k_attn(
    const U16* __restrict__ qbf, const U16* __restrict__ kbf, const U16* __restrict__ vt,
    const float* __restrict__ bias_full, U16* __restrict__ aout)
{
    __shared__ U16 plds[64*PST];      // 29696 B
    __shared__ U16 vlds[28*64*8];     // 28672 B, chunk-major [ch][row][8]
    const int bh = blockIdx.x;
    const int b  = bh / NH, h = bh - b*NH;
    const int tid = threadIdx.x, lane = tid & 63, w = tid >> 6;
    const int l15 = lane & 15, oct = lane >> 4;

    // stage v: 7 rounds x 256 threads x 16B; per wave: ch = r*4+w fixed, row = lane
    {
        const U16* vsrc = vt + (size_t)bh*DV*NPAD;
#pragma unroll
        for (int r=0;r<7;++r){
            int slot = r*256 + tid;
            __builtin_amdgcn_global_load_lds((const AS1 U32*)(vsrc + (size_t)(slot & 63)*NPAD + (slot >> 6)*8),
                (AS3 U32*)(vlds + (size_t)(r*256 + w*64)*8), 16, 0, 0);
        }
    }

    // q fragment (B operand, col = l15): this lane's q index
    const int qg = w*16 + l15;
    bf8 qf = bf8zero();
    if (qg < NQ) qf = *(const bf8*)(qbf + ((size_t)(b*NQ + qg))*INDIM + h*HKD + oct*8);

    // QK^T swapped: C = attn^T tiles (rows = n, cols = q)
    f4 acc[13];
#pragma unroll
    for (int mt=0;mt<13;++mt) acc[mt] = f4zero();
#pragma unroll
    for (int mt=0;mt<13;++mt){
        int n = mt*16 + l15;
        bf8 kf = bf8zero();
        if (n < NTOK) kf = *(const bf8*)(kbf + ((size_t)bh*NTOK + n)*HKD + oct*8);
        acc[mt] = __builtin_amdgcn_mfma_f32_16x16x32_bf16(kf, qf, acc[mt], 0, 0, 0);
    }

    const float scale = 0.17677669529663689f;   // 1/sqrt(32)
    float mx = -1e30f;
#pragma unroll
    for (int mt=0;mt<13;++mt){
        f4 bi4 = f4zero();
        if (qg < NQ) bi4 = *(const f4*)(bias_full + ((size_t)h*NQ + qg)*NTOK + mt*16 + oct*4);
#pragma unroll
        for (int r=0;r<4;++r){
            int n = mt*16 + oct*4 + r;
            float s = (n < NTOK) ? acc[mt][r]*scale + bi4[r] : -1e30f;
            acc[mt][r] = s;
            mx = fmaxf(mx, s);
        }
    }
    mx = fmaxf(mx, __shfl_xor(mx, 16));
    mx = fmaxf(mx, __shfl_xor(mx, 32));

    float sum = 0.f;
#pragma unroll
    for (int mt=0;mt<13;++mt){
#pragma unroll
        for (int r=0;r<4;++r){
            int n = mt*16 + oct*4 + r;
            float p = (n < NTOK) ? __expf(acc[mt][r] - mx) : 0.f;
            acc[mt][r] = p;
            sum += p;
        }
    }
    sum += __shfl_xor(sum, 16);
    sum += __shfl_xor(sum, 32);
    const float inv = 1.f / sum;

    // write P (bf16) into LDS in PV A-fragment layout: row = q, cols n
    const int prow = w*16 + l15;
#pragma unroll
    for (int mt=0;mt<13;++mt){
        u16x4 pk;
#pragma unroll
        for (int r=0;r<4;++r) pk[r] = f2bf(acc[mt][r]*inv);
        *(u16x4*)(plds + prow*PST + mt*16 + oct*4) = pk;
    }
    if (oct == 0){
#pragma unroll
        for (int c=208;c<224;++c) plds[prow*PST + c] = 0;
    }
    __syncthreads();   // drains vmcnt(0) too -> vlds ready

    // PV: out(q,d) = P(q,n) @ v(n,d); A from LDS, B = v^T from LDS (chunk-major)
    f4 pacc[4];
#pragma unroll
    for (int dt=0;dt<4;++dt) pacc[dt] = f4zero();
#pragma unroll
    for (int kt=0;kt<7;++kt){
        bf8 pa = *(const bf8*)(plds + prow*PST + kt*32 + oct*8);
#pragma unroll
        for (int dt=0;dt<4;++dt){
            bf8 vf = *(const bf8*)(vlds + (size_t)((kt*4+oct)*64 + dt*16 + l15)*8);
            pacc[dt] = __builtin_amdgcn_mfma_f32_16x16x32_bf16(pa, vf, pacc[dt], 0, 0, 0);
        }
    }

    // epilogue: hard_swish, store bf16 (b, q, h*64+d)
#pragma unroll
    for (int dt=0;dt<4;++dt){
#pragma unroll
        for (int r=0;r<4;++r){
            int qo = w*16 + oct*4 + r;
            if (qo < NQ){
                int d = dt*16 + l15;
                float v = pacc[dt][r];
                float t = fminf(fmaxf(v + 3.f, 0.f), 6.f);
                aout[((size_t)(b*NQ + qo))*DHD + h*DV + d] = f2bf(v * t * (1.f/6.f));
            }
        }
    }
}

// ---------------- launch ----------------
extern "C" void kernel_launch(void* const* d_in, const int* in_sizes, int n_in,
                              void* d_out, int out_size, void* d_ws, size_t ws_size,
                              hipStream_t stream)
{
    const float* x    = (const float*)d_in[0];
    const float* kv_w = (const float*)d_in[1];
    const float* kv_g = (const float*)d_in[2];
    const float* kv_b = (const float*)d_in[3];
    const float* kv_m = (const float*)d_in[4];
    const float* kv_v = (const float*)d_in[5];
    const float* q_w  = (const float*)d_in[6];
    const float* q_g  = (const float*)d_in[7];
    const float* q_b  = (const float*)d_in[8];
    const float* q_m  = (const float*)d_in[9];
    const float* q_v  = (const float*)d_in[10];
    const float* pr_w = (const float*)d_in[11];
    const float* pr_g = (const float*)d_in[12];
    const float* pr_b = (const float*)d_in[13];
    const float* pr_m = (const float*)d_in[14];
    const float* pr_v = (const float*)d_in[15];
    const float* ab   = (const float*)d_in[16];
    const int*  idxs  = (const int*)d_in[17];
    const int n_off = in_sizes[16] / NH;

    char* ws = (char*)d_ws;
    size_t off = 0;
    auto alloc = [&](size_t bytes)->char*{
        char* p = ws + off; off += (bytes + 255) & ~(size_t)255; return p;
    };
    U16*   x_bf   = (U16*)  alloc((size_t)BSZ*NTOK*INDIM*2);   // 38.5 MB
    U16*   xs_bf  = (U16*)  alloc((size_t)BSZ*NQ*INDIM*2);     // 9.6 MB
    U16*   kvw_bf = (U16*)  alloc((size_t)KVH*INDIM*2);
    U16*   qw_bf  = (U16*)  alloc((size_t)INDIM*INDIM*2);
    U16*   prw_bf = (U16*)  alloc((size_t)OUTD*DHD*2);
    float* s_kv   = (float*)alloc(KVH*4);
    float* b_kv   = (float*)alloc(KVH*4);
    float* s_q    = (float*)alloc(INDIM*4);
    float* b_q    = (float*)alloc(INDIM*4);
    float* s_pr   = (float*)alloc(OUTD*4);
    float* b_pr   = (float*)alloc(OUTD*4);
    float* biasf  = (float*)alloc(((size_t)NH*NQ*NTOK + 256)*4);  // +pad for f4 tail reads
    U16*   k_bf   = (U16*)  alloc((size_t)BSZ*NH*NTOK*HKD*2);  // 38.5 MB
    U16*   v_t    = (U16*)  alloc((size_t)BSZ*NH*DV*NPAD*2);   // 88 MB
    U16*   q_out  = (U16*)  alloc((size_t)BSZ*NQ*INDIM*2);     // 9.6 MB
    U16*   a_out  = (U16*)  alloc((size_t)BSZ*NQ*DHD*2);       // 19.3 MB
    if (off > ws_size) return;  // insufficient workspace: fail visibly (no OOB writes)

    // prep (4 launches)
    {
        int n8 = BSZ*NTOK*INDIM/8;
        k_cast8<<<(n8+255)/256, 256, 0, stream>>>(x, x_bf, n8);
    }
    {
        int n8 = BSZ*NQ*INDIM/8;
        k_castxs<<<(n8+255)/256, 256, 0, stream>>>(x, xs_bf, n8);
    }
    k_castw<<<(W1C+W2C+W3C+255)/256, 256, 0, stream>>>(kv_w, q_w, pr_w, kvw_bf, qw_bf, prw_bf);
    k_misc<<<BIAS_BLK+BN_BLK+VTZ_BLK, 256, 0, stream>>>(
        ab, idxs, n_off,
        kv_g, kv_b, kv_m, kv_v, q_g, q_b, q_m, q_v, pr_g, pr_b, pr_m, pr_v,
        s_kv, b_kv, s_q, b_q, s_pr, b_pr, biasf, v_t);

    // kv GEMM: (50176 x 1152 x 384); grid (N-tiles, M-tiles)
    {
        dim3 g(KVH/128, BSZ*NTOK/128);
        k_gemm<0, INDIM/64><<<g, 256, 0, stream>>>(x_bf, kvw_bf, s_kv, b_kv, k_bf, v_t, nullptr,
                                                   BSZ*NTOK, KVH, INDIM);
    }
    // q GEMM: (12544 x 384 x 384)
    {
        dim3 g(INDIM/128, BSZ*NQ/128);
        k_gemm<1, INDIM/64><<<g, 256, 0, stream>>>(xs_bf, qw_bf, s_q, b_q, q_out, nullptr, nullptr,
                                                   BSZ*NQ, INDIM, INDIM);
    }
    // attention + hard_swish
    k_attn<<<BSZ*NH, 256, 0, stream>>>(q_out, k_bf, v_t, biasf, a_out);
    // proj GEMM: (12544 x 512 x 768) -> f32 out
    {
        dim3 g(OUTD/128, BSZ*NQ/128);
        k_gemm<2, DHD/64><<<g, 256, 0, stream>>>(a_out, prw_bf, s_pr, b_pr, nullptr, nullptr,
                                                 (float*)d_out, BSZ*NQ, OUTD, DHD);
    }
}

// Round 6
// 216.139 us; speedup vs baseline: 1.4189x; 1.1451x over previous
//
#include <hip/hip_runtime.h>
#include <hip/hip_bf16.h>
#include <math.h>

typedef unsigned short U16;
typedef unsigned int U32;
typedef __attribute__((ext_vector_type(8))) short bf8;        // 8 x bf16 (MFMA A/B frag)
typedef __attribute__((ext_vector_type(4))) float f4;         // MFMA C/D frag
typedef __attribute__((ext_vector_type(4))) unsigned short u16x4;

#define AS1 __attribute__((address_space(1)))
#define AS3 __attribute__((address_space(3)))

// ---- constants ----
#define BSZ   256
#define NTOK  196
#define NQ    49
#define INDIM 384
#define OUTD  512
#define NH    12
#define DV    64
#define DHD   768
#define KVH   1152

// fused kernel LDS map (u16 offsets inside 64KB smem = 32768 u16)
// GEMM phase: A0 [0,8192) A1 [8192,16384) B0 [16384,20480) B1 [20480,24576)
// post-GEMM (aliases staging, all dead after final barrier):
//   KL k_lds  [0,7168):      [4 dch][224 n][8]
//   QL q_lds  [7168,9216):   [4 dch][64 qg][8]
//   VL v_lds  [9216,23552):  [28 nch][64 d][8]
// plds (after QK^T): rows 0-31 at PA [24576,31744), rows 32-63 at [0,7168) (=KL, dead)
#define FA0 0
#define FA1 8192
#define FB0 16384
#define FB1 20480
#define KL  0
#define QL  7168
#define VL  9216
#define PA  24576
#define FNK 12     // 384/32 K-steps

__device__ inline U16 f2bf(float f){
    __hip_bfloat16 h = __float2bfloat16(f);
    return *(U16*)&h;
}
__device__ inline f4 f4zero(){ f4 z; z[0]=0.f; z[1]=0.f; z[2]=0.f; z[3]=0.f; return z; }

// ---------------- prep kernels ----------------
__global__ void k_cast8(const float* __restrict__ in, U16* __restrict__ out, int n8){
    int i = blockIdx.x*256 + threadIdx.x;
    if (i >= n8) return;
    const float* p = in + (size_t)i*8;
    U16 o[8];
#pragma unroll
    for (int j=0;j<8;++j) o[j] = f2bf(p[j]);
    *(bf8*)(out + (size_t)i*8) = *(const bf8*)o;
}

// all three weight casts in one launch
#define W1C (KVH*INDIM/8)            // 55296
#define W2C (INDIM*INDIM/8)          // 18432
#define W3C (OUTD*DHD/8)             // 49152
__global__ void k_castw(const float* __restrict__ w1, const float* __restrict__ w2,
                        const float* __restrict__ w3, U16* __restrict__ o1,
                        U16* __restrict__ o2, U16* __restrict__ o3){
    int i = blockIdx.x*256 + threadIdx.x;
    const float* p; U16* o;
    if (i < W1C){ p = w1 + (size_t)i*8; o = o1 + (size_t)i*8; }
    else if (i < W1C+W2C){ int k=i-W1C; p = w2 + (size_t)k*8; o = o2 + (size_t)k*8; }
    else if (i < W1C+W2C+W3C){ int k=i-W1C-W2C; p = w3 + (size_t)k*8; o = o3 + (size_t)k*8; }
    else return;
    U16 t[8];
#pragma unroll
    for (int j=0;j<8;++j) t[j] = f2bf(p[j]);
    *(bf8*)o = *(const bf8*)t;
}

// bias expand + BN folds, one launch (block-range dispatch)
#define BIAS_N   (NH*NQ*NTOK)        // 115248
#define BIAS_BLK ((BIAS_N+255)/256)  // 451
#define BN_N     (KVH+INDIM+OUTD)    // 2048
#define BN_BLK   (BN_N/256)          // 8
__global__ void k_misc(const float* __restrict__ ab, const int* __restrict__ idxs, int n_off,
                       const float* __restrict__ g1, const float* __restrict__ b1,
                       const float* __restrict__ m1, const float* __restrict__ v1,
                       const float* __restrict__ g2, const float* __restrict__ b2,
                       const float* __restrict__ m2, const float* __restrict__ v2,
                       const float* __restrict__ g3, const float* __restrict__ b3,
                       const float* __restrict__ m3, const float* __restrict__ v3,
                       float* __restrict__ s1, float* __restrict__ bo1,
                       float* __restrict__ s2, float* __restrict__ bo2,
                       float* __restrict__ s3, float* __restrict__ bo3,
                       float* __restrict__ bias_out){
    int blk = blockIdx.x;
    int tid = threadIdx.x;
    if (blk < BIAS_BLK){
        int i = blk*256 + tid;
        if (i < BIAS_N){
            int h = i / (NQ*NTOK);
            int qk = i - h*(NQ*NTOK);
            bias_out[i] = ab[h*n_off + idxs[qk]];
        }
    } else {
        int i = (blk-BIAS_BLK)*256 + tid;
        const float *g,*b,*m,*v; float *so,*bo; int k;
        if (i < KVH){ g=g1;b=b1;m=m1;v=v1;so=s1;bo=bo1;k=i; }
        else if (i < KVH+INDIM){ g=g2;b=b2;m=m2;v=v2;so=s2;bo=bo2;k=i-KVH; }
        else { g=g3;b=b3;m=m3;v=v3;so=s3;bo=bo3;k=i-KVH-INDIM; }
        float s = g[k] / sqrtf(v[k] + 1e-5f);
        so[k] = s;
        bo[k] = b[k] - m[k]*s;
    }
}

// ---------------- fused kv-GEMM + q-GEMM + attention, one block per (b,h) ----------------
// GEMM: C[256 rows of x[b] (rows>=196 are finite garbage)][128 cols = k(32)|v(64)|q(32)]
// counted-vmcnt double-buffered K-loop (6 loads/wave/step), then attention from LDS.
__global__ __launch_bounds__(256,2) void k_fused(
    const U16* __restrict__ xbf, const U16* __restrict__ kvw, const U16* __restrict__ qw,
    const float* __restrict__ skv, const float* __restrict__ bkv,
    const float* __restrict__ sq,  const float* __restrict__ bq,
    const float* __restrict__ biasf, U16* __restrict__ aout)
{
    __shared__ U16 smem[32768];   // 64 KB
    const int bh = blockIdx.x;
    const int b  = bh / NH, h = bh - b*NH;
    const int tid = threadIdx.x, lane = tid & 63, w = tid >> 6;
    const int wm = w >> 1, wn = w & 1;
    const int l15 = lane & 15, oct = lane >> 4;

    U16* Ab[2] = { smem + FA0, smem + FA1 };
    U16* Bb[2] = { smem + FB0, smem + FB1 };

    // A staging: slot = c*256+tid -> row=tid, chunk=c (4 chunks of 8 u16 = FK 32)
    const U16* abase = xbf + ((size_t)(b*NTOK + tid))*INDIM;
    // B staging: slot = c*256+tid -> row=tid&127, chunk=c*2+(tid>>7)
    const U16* bsrc[2];
    {
        int row = tid & 127;
#pragma unroll
        for (int c=0;c<2;++c){
            int ch = c*2 + (tid>>7);
            bsrc[c] = (row < 96) ? kvw + ((size_t)(h*96 + row))*INDIM + ch*8
                                 : qw  + ((size_t)(h*32 + (row-96)))*INDIM + ch*8;
        }
    }

    f4 acc[8][4];
#pragma unroll
    for (int i=0;i<8;++i)
#pragma unroll
        for (int j=0;j<4;++j) acc[i][j] = f4zero();

    // prologue: stage tile 0 into buf 0 (6 loads)
#pragma unroll
    for (int c=0;c<4;++c)
        __builtin_amdgcn_global_load_lds((const AS1 U32*)(abase + c*8),
            (AS3 U32*)(Ab[0] + (c*256+tid)*8), 16, 0, 0);
#pragma unroll
    for (int c=0;c<2;++c)
        __builtin_amdgcn_global_load_lds((const AS1 U32*)(bsrc[c]),
            (AS3 U32*)(Bb[0] + (c*256+tid)*8), 16, 0, 0);

#pragma unroll
    for (int kt=0; kt<FNK; ++kt){
        const int cur = kt & 1;
        if (kt+1 < FNK){
            const int kb = (kt+1)*32;
#pragma unroll
            for (int c=0;c<4;++c)
                __builtin_amdgcn_global_load_lds((const AS1 U32*)(abase + kb + c*8),
                    (AS3 U32*)(Ab[cur^1] + (c*256+tid)*8), 16, 0, 0);
#pragma unroll
            for (int c=0;c<2;++c)
                __builtin_amdgcn_global_load_lds((const AS1 U32*)(bsrc[c] + kb),
                    (AS3 U32*)(Bb[cur^1] + (c*256+tid)*8), 16, 0, 0);
            asm volatile("s_waitcnt vmcnt(6)" ::: "memory");   // tile kt landed; kt+1 in flight
        } else {
            asm volatile("s_waitcnt vmcnt(0)" ::: "memory");
        }
        __builtin_amdgcn_sched_barrier(0);
        __builtin_amdgcn_s_barrier();
        __builtin_amdgcn_sched_barrier(0);

        bf8 af[8], bfr[4];
#pragma unroll
        for (int i=0;i<8;++i)
            af[i]  = *(const bf8*)(Ab[cur] + (oct*256 + wm*128 + i*16 + l15)*8);
#pragma unroll
        for (int j=0;j<4;++j)
            bfr[j] = *(const bf8*)(Bb[cur] + (oct*128 + wn*64 + j*16 + l15)*8);
        __builtin_amdgcn_s_setprio(1);
#pragma unroll
        for (int i=0;i<8;++i)
#pragma unroll
            for (int j=0;j<4;++j)
                acc[i][j] = __builtin_amdgcn_mfma_f32_16x16x32_bf16(af[i], bfr[j], acc[i][j], 0, 0, 0);
        __builtin_amdgcn_s_setprio(0);
        __builtin_amdgcn_sched_barrier(0);
        __builtin_amdgcn_s_barrier();       // buf `cur` free for next iteration's staging
        __builtin_amdgcn_sched_barrier(0);
    }

    // ---- epilogue: BN fold, scatter acc -> k/q/v LDS regions (alias staging) ----
#pragma unroll
    for (int j=0;j<4;++j){
        const int c = wn*64 + j*16 + l15;             // 0..127
        float sc, bi;
        if (c < 96){ sc = skv[h*96 + c]; bi = bkv[h*96 + c]; }
        else       { sc = sq[h*32 + (c-96)]; bi = bq[h*32 + (c-96)]; }
#pragma unroll
        for (int i=0;i<8;++i){
            if (wm == 1 && i >= 6) continue;          // rows 224..255 discarded
            const int n0 = wm*128 + i*16 + oct*4;
            if (c < 32){
#pragma unroll
                for (int r=0;r<4;++r)
                    smem[KL + ((c>>3)*224 + (n0+r))*8 + (c&7)] = f2bf(acc[i][j][r]*sc + bi);
            } else if (c < 96){
                const int dv = c - 32;
                u16x4 pk;
#pragma unroll
                for (int r=0;r<4;++r) pk[r] = f2bf(acc[i][j][r]*sc + bi);
                *(u16x4*)(smem + VL + ((n0>>3)*64 + dv)*8 + (oct&1)*4) = pk;
            } else {
                const int dq = c - 96;
#pragma unroll
                for (int r=0;r<4;++r){
                    const int n = n0 + r;
                    if (n < 196 && (n & 1) == 0){
                        const int dn = n / 28, nm = n - dn*28;
                        if (nm < 14){
                            const int qg2 = dn*7 + (nm >> 1);
                            smem[QL + ((dq>>3)*64 + qg2)*8 + (dq&7)] = f2bf(acc[i][j][r]*sc + bi);
                        }
                    }
                }
            }
        }
    }
    __syncthreads();   // k/q/v visible to all waves

    // ---- attention: wave w owns q columns qg = w*16 + l15 ----
    const int qg = w*16 + l15;
    const bf8 qf = *(const bf8*)(smem + QL + (oct*64 + qg)*8);  // qg>=49 -> finite garbage

    f4 sacc[14];
#pragma unroll
    for (int mt=0;mt<14;++mt) sacc[mt] = f4zero();
#pragma unroll
    for (int mt=0;mt<14;++mt){
        const bf8 kf = *(const bf8*)(smem + KL + (oct*224 + mt*16 + l15)*8);
        sacc[mt] = __builtin_amdgcn_mfma_f32_16x16x32_bf16(kf, qf, sacc[mt], 0, 0, 0);
    }
    __syncthreads();   // KL/QL dead; plds regions safe to write

    const float scale = 0.17677669529663689f;   // 1/sqrt(32)
    float mx = -1e30f;
#pragma unroll
    for (int mt=0;mt<14;++mt){
        const int n0 = mt*16 + oct*4;
        f4 bi4 = f4zero();
        if (qg < NQ && n0 < 196) bi4 = *(const f4*)(biasf + ((size_t)h*NQ + qg)*NTOK + n0);
#pragma unroll
        for (int r=0;r<4;++r){
            float s = (n0 + r < NTOK) ? sacc[mt][r]*scale + bi4[r] : -1e30f;
            sacc[mt][r] = s;
            mx = fmaxf(mx, s);
        }
    }
    mx = fmaxf(mx, __shfl_xor(mx, 16));
    mx = fmaxf(mx, __shfl_xor(mx, 32));

    float sum = 0.f;
#pragma unroll
    for (int mt=0;mt<14;++mt){
#pragma unroll
        for (int r=0;r<4;++r){
            float p = (mt*16 + oct*4 + r < NTOK) ? __expf(sacc[mt][r] - mx) : 0.f;
            sacc[mt][r] = p;
            sum += p;
        }
    }
    sum += __shfl_xor(sum, 16);
    sum += __shfl_xor(sum, 32);
    const float inv = 1.f / sum;

    // P -> plds (bf16), split regions, XOR-swizzled 8-u16 block index
    const int prow = w*16 + l15;
    const int pbase = ((w < 2) ? PA : 0) + (prow & 31)*224;
    const int psw = prow & 3;
#pragma unroll
    for (int mt=0;mt<14;++mt){
        u16x4 pk;
#pragma unroll
        for (int r=0;r<4;++r) pk[r] = f2bf(sacc[mt][r]*inv);
        const int blk = (mt*2 + (oct>>1)) ^ psw;
        *(u16x4*)(smem + pbase + blk*8 + (oct&1)*4) = pk;
    }
    // own-wave rows only -> no barrier needed before PV

    // PV: out(q,d) = P(q,n) @ v(n,d)
    f4 pacc[4];
#pragma unroll
    for (int dt=0;dt<4;++dt) pacc[dt] = f4zero();
#pragma unroll
    for (int kt=0;kt<7;++kt){
        const bf8 pa = *(const bf8*)(smem + pbase + ((kt*4 + oct) ^ psw)*8);
#pragma unroll
        for (int dt=0;dt<4;++dt){
            const bf8 vf = *(const bf8*)(smem + VL + ((kt*4 + oct)*64 + dt*16 + l15)*8);
            pacc[dt] = __builtin_amdgcn_mfma_f32_16x16x32_bf16(pa, vf, pacc[dt], 0, 0, 0);
        }
    }

    // hard_swish, store bf16 (b, q, h*64+d)
#pragma unroll
    for (int dt=0;dt<4;++dt){
#pragma unroll
        for (int r=0;r<4;++r){
            const int qo = w*16 + oct*4 + r;
            if (qo < NQ){
                const int d = dt*16 + l15;
                float v = pacc[dt][r];
                float t = fminf(fmaxf(v + 3.f, 0.f), 6.f);
                aout[((size_t)(b*NQ + qo))*DHD + h*DV + d] = f2bf(v * t * (1.f/6.f));
            }
        }
    }
}

// ---------------- proj GEMM 128x128x64, counted-vmcnt double buffer ----------------
__global__ __launch_bounds__(256,2) void k_proj(
    const U16* __restrict__ A, const U16* __restrict__ Bw,
    const float* __restrict__ s_arr, const float* __restrict__ b_arr,
    float* __restrict__ o32)
{
    __shared__ U16 smem[32768];
    U16* Ab[2] = { smem,          smem + 8192 };
    U16* Bb[2] = { smem + 16384,  smem + 24576 };
    const int tid  = threadIdx.x;
    const int lane = tid & 63;
    const int w    = tid >> 6;
    const int wm   = w >> 1, wn = w & 1;
    const int l15  = lane & 15, oct = lane >> 4;
    const int gn0  = blockIdx.x * 128;
    const int gm0  = blockIdx.y * 128;

    f4 acc[4][4];
#pragma unroll
    for (int i=0;i<4;++i)
#pragma unroll
        for (int j=0;j<4;++j) acc[i][j] = f4zero();

    size_t aoff[4], boff[4];
#pragma unroll
    for (int c=0;c<4;++c){
        int slot = c*256 + tid;
        int row = slot & 127, ch = slot >> 7;
        aoff[c] = (size_t)(gm0 + row)*DHD + ch*8;
        boff[c] = (size_t)(gn0 + row)*DHD + ch*8;
    }

#pragma unroll
    for (int c=0;c<4;++c){
        __builtin_amdgcn_global_load_lds((const AS1 U32*)(A + aoff[c]),
            (AS3 U32*)(Ab[0] + (c*256+tid)*8), 16, 0, 0);
        __builtin_amdgcn_global_load_lds((const AS1 U32*)(Bw + boff[c]),
            (AS3 U32*)(Bb[0] + (c*256+tid)*8), 16, 0, 0);
    }

#pragma unroll
    for (int kt=0; kt<12; ++kt){
        const int cur = kt & 1;
        if (kt+1 < 12){
            const int kb = (kt+1)*64;
#pragma unroll
            for (int c=0;c<4;++c){
                __builtin_amdgcn_global_load_lds((const AS1 U32*)(A + aoff[c] + kb),
                    (AS3 U32*)(Ab[cur^1] + (c*256+tid)*8), 16, 0, 0);
                __builtin_amdgcn_global_load_lds((const AS1 U32*)(Bw + boff[c] + kb),
                    (AS3 U32*)(Bb[cur^1] + (c*256+tid)*8), 16, 0, 0);
            }
            asm volatile("s_waitcnt vmcnt(8)" ::: "memory");
        } else {
            asm volatile("s_waitcnt vmcnt(0)" ::: "memory");
        }
        __builtin_amdgcn_sched_barrier(0);
        __builtin_amdgcn_s_barrier();
        __builtin_amdgcn_sched_barrier(0);

#pragma unroll
        for (int kk=0;kk<2;++kk){
            bf8 af[4], bfr[4];
#pragma unroll
            for (int i=0;i<4;++i)
                af[i]  = *(const bf8*)(Ab[cur] + ((kk*4+oct)*128 + wm*64 + i*16 + l15)*8);
#pragma unroll
            for (int j=0;j<4;++j)
                bfr[j] = *(const bf8*)(Bb[cur] + ((kk*4+oct)*128 + wn*64 + j*16 + l15)*8);
            __builtin_amdgcn_s_setprio(1);
#pragma unroll
            for (int i=0;i<4;++i)
#pragma unroll
                for (int j=0;j<4;++j)
                    acc[i][j] = __builtin_amdgcn_mfma_f32_16x16x32_bf16(af[i], bfr[j], acc[i][j], 0, 0, 0);
            __builtin_amdgcn_s_setprio(0);
        }
        __builtin_amdgcn_sched_barrier(0);
        __builtin_amdgcn_s_barrier();
        __builtin_amdgcn_sched_barrier(0);
    }

#pragma unroll
    for (int j=0;j<4;++j){
        const int col = gn0 + wn*64 + j*16 + l15;
        const float sc = s_arr[col];
        const float bi = b_arr[col];
#pragma unroll
        for (int i=0;i<4;++i){
            const int row0 = gm0 + wm*64 + i*16 + oct*4;
#pragma unroll
            for (int r=0;r<4;++r)
                o32[(size_t)(row0+r)*OUTD + col] = acc[i][j][r]*sc + bi;
        }
    }
}

// ---------------- launch ----------------
extern "C" void kernel_launch(void* const* d_in, const int* in_sizes, int n_in,
                              void* d_out, int out_size, void* d_ws, size_t ws_size,
                              hipStream_t stream)
{
    const float* x    = (const float*)d_in[0];
    const float* kv_w = (const float*)d_in[1];
    const float* kv_g = (const float*)d_in[2];
    const float* kv_b = (const float*)d_in[3];
    const float* kv_m = (const float*)d_in[4];
    const float* kv_v = (const float*)d_in[5];
    const float* q_w  = (const float*)d_in[6];
    const float* q_g  = (const float*)d_in[7];
    const float* q_b  = (const float*)d_in[8];
    const float* q_m  = (const float*)d_in[9];
    const float* q_v  = (const float*)d_in[10];
    const float* pr_w = (const float*)d_in[11];
    const float* pr_g = (const float*)d_in[12];
    const float* pr_b = (const float*)d_in[13];
    const float* pr_m = (const float*)d_in[14];
    const float* pr_v = (const float*)d_in[15];
    const float* ab   = (const float*)d_in[16];
    const int*  idxs  = (const int*)d_in[17];
    const int n_off = in_sizes[16] / NH;

    char* ws = (char*)d_ws;
    size_t off = 0;
    auto alloc = [&](size_t bytes)->char*{
        char* p = ws + off; off += (bytes + 255) & ~(size_t)255; return p;
    };
    U16*   x_bf   = (U16*)  alloc((size_t)BSZ*NTOK*INDIM*2);   // 38.5 MB
    U16*   kvw_bf = (U16*)  alloc((size_t)KVH*INDIM*2);
    U16*   qw_bf  = (U16*)  alloc((size_t)INDIM*INDIM*2);
    U16*   prw_bf = (U16*)  alloc((size_t)OUTD*DHD*2);
    float* s_kv   = (float*)alloc(KVH*4);
    float* b_kv   = (float*)alloc(KVH*4);
    float* s_q    = (float*)alloc(INDIM*4);
    float* b_q    = (float*)alloc(INDIM*4);
    float* s_pr   = (float*)alloc(OUTD*4);
    float* b_pr   = (float*)alloc(OUTD*4);
    float* biasf  = (float*)alloc(((size_t)NH*NQ*NTOK + 256)*4);  // +pad for f4 tail reads
    U16*   a_out  = (U16*)  alloc((size_t)BSZ*NQ*DHD*2);       // 19.3 MB
    if (off > ws_size) return;  // insufficient workspace: fail visibly (no OOB writes)

    // prep (3 launches)
    {
        int n8 = BSZ*NTOK*INDIM/8;
        k_cast8<<<(n8+255)/256, 256, 0, stream>>>(x, x_bf, n8);
    }
    k_castw<<<(W1C+W2C+W3C+255)/256, 256, 0, stream>>>(kv_w, q_w, pr_w, kvw_bf, qw_bf, prw_bf);
    k_misc<<<BIAS_BLK+BN_BLK, 256, 0, stream>>>(
        ab, idxs, n_off,
        kv_g, kv_b, kv_m, kv_v, q_g, q_b, q_m, q_v, pr_g, pr_b, pr_m, pr_v,
        s_kv, b_kv, s_q, b_q, s_pr, b_pr, biasf);

    // fused kv-GEMM + q-GEMM + attention + hard_swish
    k_fused<<<BSZ*NH, 256, 0, stream>>>(x_bf, kvw_bf, qw_bf, s_kv, b_kv, s_q, b_q,
                                        biasf, a_out);

    // proj GEMM: (12544 x 512 x 768) -> f32 out
    {
        dim3 g(OUTD/128, BSZ*NQ/128);
        k_proj<<<g, 256, 0, stream>>>(a_out, prw_bf, s_pr, b_pr, (float*)d_out);
    }
}

// Round 7
// 216.008 us; speedup vs baseline: 1.4198x; 1.0006x over previous
//
#include <hip/hip_runtime.h>
#include <hip/hip_bf16.h>
#include <math.h>

typedef unsigned short U16;
typedef unsigned int U32;
typedef __attribute__((ext_vector_type(8))) short bf8;        // 8 x bf16 (MFMA A/B frag)
typedef __attribute__((ext_vector_type(4))) float f4;         // MFMA C/D frag
typedef __attribute__((ext_vector_type(4))) unsigned short u16x4;

#define AS1 __attribute__((address_space(1)))
#define AS3 __attribute__((address_space(3)))

// ---- constants ----
#define BSZ   256
#define NTOK  196
#define NQ    49
#define INDIM 384
#define OUTD  512
#define NH    12
#define DV    64
#define DHD   768
#define KVH   1152

// fused kernel LDS map (u16 offsets inside 64KB smem = 32768 u16)
// GEMM phase: A0 [0,8192) A1 [8192,16384) B0 [16384,20480) B1 [20480,24576)
// post-GEMM (aliases staging, all dead after final barrier):
//   KL k_lds  [0,7168):      [4 dch][224 n][8]
//   QL q_lds  [7168,9216):   [4 dch][64 qg][8]
//   VL v_lds  [9216,23552):  [28 nch][64 d][8]
// plds (after QK^T): rows 0-31 at PA [24576,31744), rows 32-63 at [0,7168) (=KL, dead)
#define FA0 0
#define FA1 8192
#define FB0 16384
#define FB1 20480
#define KL  0
#define QL  7168
#define VL  9216
#define PA  24576
#define FNK 12     // 384/32 K-steps

__device__ inline U16 f2bf(float f){
    __hip_bfloat16 h = __float2bfloat16(f);
    return *(U16*)&h;
}
__device__ inline f4 f4zero(){ f4 z; z[0]=0.f; z[1]=0.f; z[2]=0.f; z[3]=0.f; return z; }

// ---------------- prep kernels ----------------
__global__ void k_cast8(const float* __restrict__ in, U16* __restrict__ out, int n8){
    int i = blockIdx.x*256 + threadIdx.x;
    if (i >= n8) return;
    const float* p = in + (size_t)i*8;
    U16 o[8];
#pragma unroll
    for (int j=0;j<8;++j) o[j] = f2bf(p[j]);
    *(bf8*)(out + (size_t)i*8) = *(const bf8*)o;
}

// all three weight casts in one launch
#define W1C (KVH*INDIM/8)            // 55296
#define W2C (INDIM*INDIM/8)          // 18432
#define W3C (OUTD*DHD/8)             // 49152
__global__ void k_castw(const float* __restrict__ w1, const float* __restrict__ w2,
                        const float* __restrict__ w3, U16* __restrict__ o1,
                        U16* __restrict__ o2, U16* __restrict__ o3){
    int i = blockIdx.x*256 + threadIdx.x;
    const float* p; U16* o;
    if (i < W1C){ p = w1 + (size_t)i*8; o = o1 + (size_t)i*8; }
    else if (i < W1C+W2C){ int k=i-W1C; p = w2 + (size_t)k*8; o = o2 + (size_t)k*8; }
    else if (i < W1C+W2C+W3C){ int k=i-W1C-W2C; p = w3 + (size_t)k*8; o = o3 + (size_t)k*8; }
    else return;
    U16 t[8];
#pragma unroll
    for (int j=0;j<8;++j) t[j] = f2bf(p[j]);
    *(bf8*)o = *(const bf8*)t;
}

// bias expand + BN folds, one launch (block-range dispatch)
#define BIAS_N   (NH*NQ*NTOK)        // 115248
#define BIAS_BLK ((BIAS_N+255)/256)  // 451
#define BN_N     (KVH+INDIM+OUTD)    // 2048
#define BN_BLK   (BN_N/256)          // 8
__global__ void k_misc(const float* __restrict__ ab, const int* __restrict__ idxs, int n_off,
                       const float* __restrict__ g1, const float* __restrict__ b1,
                       const float* __restrict__ m1, const float* __restrict__ v1,
                       const float* __restrict__ g2, const float* __restrict__ b2,
                       const float* __restrict__ m2, const float* __restrict__ v2,
                       const float* __restrict__ g3, const float* __restrict__ b3,
                       const float* __restrict__ m3, const float* __restrict__ v3,
                       float* __restrict__ s1, float* __restrict__ bo1,
                       float* __restrict__ s2, float* __restrict__ bo2,
                       float* __restrict__ s3, float* __restrict__ bo3,
                       float* __restrict__ bias_out){
    int blk = blockIdx.x;
    int tid = threadIdx.x;
    if (blk < BIAS_BLK){
        int i = blk*256 + tid;
        if (i < BIAS_N){
            int h = i / (NQ*NTOK);
            int qk = i - h*(NQ*NTOK);
            bias_out[i] = ab[h*n_off + idxs[qk]];
        }
    } else {
        int i = (blk-BIAS_BLK)*256 + tid;
        const float *g,*b,*m,*v; float *so,*bo; int k;
        if (i < KVH){ g=g1;b=b1;m=m1;v=v1;so=s1;bo=bo1;k=i; }
        else if (i < KVH+INDIM){ g=g2;b=b2;m=m2;v=v2;so=s2;bo=bo2;k=i-KVH; }
        else { g=g3;b=b3;m=m3;v=v3;so=s3;bo=bo3;k=i-KVH-INDIM; }
        float s = g[k] / sqrtf(v[k] + 1e-5f);
        so[k] = s;
        bo[k] = b[k] - m[k]*s;
    }
}

// ---------------- fused kv-GEMM + q-GEMM + attention, one block per (b,h) ----------------
// GEMM: C[256 rows of x[b] (rows>=196 are finite garbage)][128 cols = k(32)|v(64)|q(32)]
// counted-vmcnt double-buffered K-loop (6 loads/wave/step), then attention from LDS.
// XCD-swizzled blockIdx: the 12 heads of one b stay on one XCD -> x panel L2-resident.
__global__ __launch_bounds__(256,2) void k_fused(
    const U16* __restrict__ xbf, const U16* __restrict__ kvw, const U16* __restrict__ qw,
    const float* __restrict__ skv, const float* __restrict__ bkv,
    const float* __restrict__ sq,  const float* __restrict__ bq,
    const float* __restrict__ biasf, U16* __restrict__ aout)
{
    __shared__ U16 smem[32768];   // 64 KB
    const int bh_hw = blockIdx.x;
    const int bh = (bh_hw & 7)*384 + (bh_hw >> 3);   // bijective XCD swizzle (3072 = 8*384)
    const int b  = bh / NH, h = bh - b*NH;
    const int tid = threadIdx.x, lane = tid & 63, w = tid >> 6;
    const int wm = w >> 1, wn = w & 1;
    const int l15 = lane & 15, oct = lane >> 4;

    U16* Ab[2] = { smem + FA0, smem + FA1 };
    U16* Bb[2] = { smem + FB0, smem + FB1 };

    // A staging: slot = c*256+tid -> row=tid, chunk=c (4 chunks of 8 u16 = FK 32)
    const U16* abase = xbf + ((size_t)(b*NTOK + tid))*INDIM;
    // B staging: slot = c*256+tid -> row=tid&127, chunk=c*2+(tid>>7)
    const U16* bsrc[2];
    {
        int row = tid & 127;
#pragma unroll
        for (int c=0;c<2;++c){
            int ch = c*2 + (tid>>7);
            bsrc[c] = (row < 96) ? kvw + ((size_t)(h*96 + row))*INDIM + ch*8
                                 : qw  + ((size_t)(h*32 + (row-96)))*INDIM + ch*8;
        }
    }

    f4 acc[8][4];
#pragma unroll
    for (int i=0;i<8;++i)
#pragma unroll
        for (int j=0;j<4;++j) acc[i][j] = f4zero();

    // prologue: stage tile 0 into buf 0 (6 loads)
#pragma unroll
    for (int c=0;c<4;++c)
        __builtin_amdgcn_global_load_lds((const AS1 U32*)(abase + c*8),
            (AS3 U32*)(Ab[0] + (c*256+tid)*8), 16, 0, 0);
#pragma unroll
    for (int c=0;c<2;++c)
        __builtin_amdgcn_global_load_lds((const AS1 U32*)(bsrc[c]),
            (AS3 U32*)(Bb[0] + (c*256+tid)*8), 16, 0, 0);

#pragma unroll
    for (int kt=0; kt<FNK; ++kt){
        const int cur = kt & 1;
        if (kt+1 < FNK){
            const int kb = (kt+1)*32;
#pragma unroll
            for (int c=0;c<4;++c)
                __builtin_amdgcn_global_load_lds((const AS1 U32*)(abase + kb + c*8),
                    (AS3 U32*)(Ab[cur^1] + (c*256+tid)*8), 16, 0, 0);
#pragma unroll
            for (int c=0;c<2;++c)
                __builtin_amdgcn_global_load_lds((const AS1 U32*)(bsrc[c] + kb),
                    (AS3 U32*)(Bb[cur^1] + (c*256+tid)*8), 16, 0, 0);
            asm volatile("s_waitcnt vmcnt(6)" ::: "memory");   // tile kt landed; kt+1 in flight
        } else {
            asm volatile("s_waitcnt vmcnt(0)" ::: "memory");
        }
        __builtin_amdgcn_sched_barrier(0);
        __builtin_amdgcn_s_barrier();
        __builtin_amdgcn_sched_barrier(0);

        bf8 af[8], bfr[4];
#pragma unroll
        for (int i=0;i<8;++i)
            af[i]  = *(const bf8*)(Ab[cur] + (oct*256 + wm*128 + i*16 + l15)*8);
#pragma unroll
        for (int j=0;j<4;++j)
            bfr[j] = *(const bf8*)(Bb[cur] + (oct*128 + wn*64 + j*16 + l15)*8);
        __builtin_amdgcn_s_setprio(1);
#pragma unroll
        for (int i=0;i<8;++i)
#pragma unroll
            for (int j=0;j<4;++j)
                acc[i][j] = __builtin_amdgcn_mfma_f32_16x16x32_bf16(af[i], bfr[j], acc[i][j], 0, 0, 0);
        __builtin_amdgcn_s_setprio(0);
        __builtin_amdgcn_sched_barrier(0);
        __builtin_amdgcn_s_barrier();       // buf `cur` free for next iteration's staging
        __builtin_amdgcn_sched_barrier(0);
    }

    // ---- epilogue: BN fold, scatter acc -> k/q/v LDS regions (alias staging) ----
#pragma unroll
    for (int j=0;j<4;++j){
        const int c = wn*64 + j*16 + l15;             // 0..127
        float sc, bi;
        if (c < 96){ sc = skv[h*96 + c]; bi = bkv[h*96 + c]; }
        else       { sc = sq[h*32 + (c-96)]; bi = bq[h*32 + (c-96)]; }
#pragma unroll
        for (int i=0;i<8;++i){
            if (wm == 1 && i >= 6) continue;          // rows 224..255 discarded
            const int n0 = wm*128 + i*16 + oct*4;
            if (c < 32){
#pragma unroll
                for (int r=0;r<4;++r)
                    smem[KL + ((c>>3)*224 + (n0+r))*8 + (c&7)] = f2bf(acc[i][j][r]*sc + bi);
            } else if (c < 96){
                const int dv = c - 32;
                u16x4 pk;
#pragma unroll
                for (int r=0;r<4;++r) pk[r] = f2bf(acc[i][j][r]*sc + bi);
                *(u16x4*)(smem + VL + ((n0>>3)*64 + dv)*8 + (oct&1)*4) = pk;
            } else {
                const int dq = c - 96;
#pragma unroll
                for (int r=0;r<4;++r){
                    const int n = n0 + r;
                    if (n < 196 && (n & 1) == 0){
                        const int dn = n / 28, nm = n - dn*28;
                        if (nm < 14){
                            const int qg2 = dn*7 + (nm >> 1);
                            smem[QL + ((dq>>3)*64 + qg2)*8 + (dq&7)] = f2bf(acc[i][j][r]*sc + bi);
                        }
                    }
                }
            }
        }
    }
    __syncthreads();   // k/q/v visible to all waves

    // ---- attention: wave w owns q columns qg = w*16 + l15 ----
    const int qg = w*16 + l15;
    const bf8 qf = *(const bf8*)(smem + QL + (oct*64 + qg)*8);  // qg>=49 -> finite garbage

    f4 sacc[14];
#pragma unroll
    for (int mt=0;mt<14;++mt) sacc[mt] = f4zero();
#pragma unroll
    for (int mt=0;mt<14;++mt){
        const bf8 kf = *(const bf8*)(smem + KL + (oct*224 + mt*16 + l15)*8);
        sacc[mt] = __builtin_amdgcn_mfma_f32_16x16x32_bf16(kf, qf, sacc[mt], 0, 0, 0);
    }
    __syncthreads();   // KL/QL dead; plds regions safe to write

    const float scale = 0.17677669529663689f;   // 1/sqrt(32)
    float mx = -1e30f;
#pragma unroll
    for (int mt=0;mt<14;++mt){
        const int n0 = mt*16 + oct*4;
        f4 bi4 = f4zero();
        if (qg < NQ && n0 < 196) bi4 = *(const f4*)(biasf + ((size_t)h*NQ + qg)*NTOK + n0);
#pragma unroll
        for (int r=0;r<4;++r){
            float s = (n0 + r < NTOK) ? sacc[mt][r]*scale + bi4[r] : -1e30f;
            sacc[mt][r] = s;
            mx = fmaxf(mx, s);
        }
    }
    mx = fmaxf(mx, __shfl_xor(mx, 16));
    mx = fmaxf(mx, __shfl_xor(mx, 32));

    float sum = 0.f;
#pragma unroll
    for (int mt=0;mt<14;++mt){
#pragma unroll
        for (int r=0;r<4;++r){
            float p = (mt*16 + oct*4 + r < NTOK) ? __expf(sacc[mt][r] - mx) : 0.f;
            sacc[mt][r] = p;
            sum += p;
        }
    }
    sum += __shfl_xor(sum, 16);
    sum += __shfl_xor(sum, 32);
    const float inv = 1.f / sum;

    // P -> plds (bf16), split regions, XOR-swizzled 8-u16 block index
    const int prow = w*16 + l15;
    const int pbase = ((w < 2) ? PA : 0) + (prow & 31)*224;
    const int psw = prow & 3;
#pragma unroll
    for (int mt=0;mt<14;++mt){
        u16x4 pk;
#pragma unroll
        for (int r=0;r<4;++r) pk[r] = f2bf(sacc[mt][r]*inv);
        const int blk = (mt*2 + (oct>>1)) ^ psw;
        *(u16x4*)(smem + pbase + blk*8 + (oct&1)*4) = pk;
    }
    // own-wave rows only -> no barrier needed before PV

    // PV: out(q,d) = P(q,n) @ v(n,d)
    f4 pacc[4];
#pragma unroll
    for (int dt=0;dt<4;++dt) pacc[dt] = f4zero();
#pragma unroll
    for (int kt=0;kt<7;++kt){
        const bf8 pa = *(const bf8*)(smem + pbase + ((kt*4 + oct) ^ psw)*8);
#pragma unroll
        for (int dt=0;dt<4;++dt){
            const bf8 vf = *(const bf8*)(smem + VL + ((kt*4 + oct)*64 + dt*16 + l15)*8);
            pacc[dt] = __builtin_amdgcn_mfma_f32_16x16x32_bf16(pa, vf, pacc[dt], 0, 0, 0);
        }
    }

    // hard_swish, store bf16 (b, q, h*64+d)
#pragma unroll
    for (int dt=0;dt<4;++dt){
#pragma unroll
        for (int r=0;r<4;++r){
            const int qo = w*16 + oct*4 + r;
            if (qo < NQ){
                const int d = dt*16 + l15;
                float v = pacc[dt][r];
                float t = fminf(fmaxf(v + 3.f, 0.f), 6.f);
                aout[((size_t)(b*NQ + qo))*DHD + h*DV + d] = f2bf(v * t * (1.f/6.f));
            }
        }
    }
}

// ---------------- proj GEMM 128x128x64, counted-vmcnt double buffer ----------------
// 1-D grid 392, XCD-swizzled: the 4 N-blocks sharing an A-panel stay on one XCD.
__global__ __launch_bounds__(256,2) void k_proj(
    const U16* __restrict__ A, const U16* __restrict__ Bw,
    const float* __restrict__ s_arr, const float* __restrict__ b_arr,
    float* __restrict__ o32)
{
    __shared__ U16 smem[32768];
    U16* Ab[2] = { smem,          smem + 8192 };
    U16* Bb[2] = { smem + 16384,  smem + 24576 };
    const int l   = (blockIdx.x & 7)*49 + (blockIdx.x >> 3);   // bijective (392 = 8*49)
    const int gn0 = (l & 3) * 128;
    const int gm0 = (l >> 2) * 128;
    const int tid  = threadIdx.x;
    const int lane = tid & 63;
    const int w    = tid >> 6;
    const int wm   = w >> 1, wn = w & 1;
    const int l15  = lane & 15, oct = lane >> 4;

    f4 acc[4][4];
#pragma unroll
    for (int i=0;i<4;++i)
#pragma unroll
        for (int j=0;j<4;++j) acc[i][j] = f4zero();

    size_t aoff[4], boff[4];
#pragma unroll
    for (int c=0;c<4;++c){
        int slot = c*256 + tid;
        int row = slot & 127, ch = slot >> 7;
        aoff[c] = (size_t)(gm0 + row)*DHD + ch*8;
        boff[c] = (size_t)(gn0 + row)*DHD + ch*8;
    }

#pragma unroll
    for (int c=0;c<4;++c){
        __builtin_amdgcn_global_load_lds((const AS1 U32*)(A + aoff[c]),
            (AS3 U32*)(Ab[0] + (c*256+tid)*8), 16, 0, 0);
        __builtin_amdgcn_global_load_lds((const AS1 U32*)(Bw + boff[c]),
            (AS3 U32*)(Bb[0] + (c*256+tid)*8), 16, 0, 0);
    }

#pragma unroll
    for (int kt=0; kt<12; ++kt){
        const int cur = kt & 1;
        if (kt+1 < 12){
            const int kb = (kt+1)*64;
#pragma unroll
            for (int c=0;c<4;++c){
                __builtin_amdgcn_global_load_lds((const AS1 U32*)(A + aoff[c] + kb),
                    (AS3 U32*)(Ab[cur^1] + (c*256+tid)*8), 16, 0, 0);
                __builtin_amdgcn_global_load_lds((const AS1 U32*)(Bw + boff[c] + kb),
                    (AS3 U32*)(Bb[cur^1] + (c*256+tid)*8), 16, 0, 0);
            }
            asm volatile("s_waitcnt vmcnt(8)" ::: "memory");
        } else {
            asm volatile("s_waitcnt vmcnt(0)" ::: "memory");
        }
        __builtin_amdgcn_sched_barrier(0);
        __builtin_amdgcn_s_barrier();
        __builtin_amdgcn_sched_barrier(0);

#pragma unroll
        for (int kk=0;kk<2;++kk){
            bf8 af[4], bfr[4];
#pragma unroll
            for (int i=0;i<4;++i)
                af[i]  = *(const bf8*)(Ab[cur] + ((kk*4+oct)*128 + wm*64 + i*16 + l15)*8);
#pragma unroll
            for (int j=0;j<4;++j)
                bfr[j] = *(const bf8*)(Bb[cur] + ((kk*4+oct)*128 + wn*64 + j*16 + l15)*8);
            __builtin_amdgcn_s_setprio(1);
#pragma unroll
            for (int i=0;i<4;++i)
#pragma unroll
                for (int j=0;j<4;++j)
                    acc[i][j] = __builtin_amdgcn_mfma_f32_16x16x32_bf16(af[i], bfr[j], acc[i][j], 0, 0, 0);
            __builtin_amdgcn_s_setprio(0);
        }
        __builtin_amdgcn_sched_barrier(0);
        __builtin_amdgcn_s_barrier();
        __builtin_amdgcn_sched_barrier(0);
    }

#pragma unroll
    for (int j=0;j<4;++j){
        const int col = gn0 + wn*64 + j*16 + l15;
        const float sc = s_arr[col];
        const float bi = b_arr[col];
#pragma unroll
        for (int i=0;i<4;++i){
            const int row0 = gm0 + wm*64 + i*16 + oct*4;
#pragma unroll
            for (int r=0;r<4;++r)
                o32[(size_t)(row0+r)*OUTD + col] = acc[i][j][r]*sc + bi;
        }
    }
}

// ---------------- launch ----------------
extern "C" void kernel_launch(void* const* d_in, const int* in_sizes, int n_in,
                              void* d_out, int out_size, void* d_ws, size_t ws_size,
                              hipStream_t stream)
{
    const float* x    = (const float*)d_in[0];
    const float* kv_w = (const float*)d_in[1];
    const float* kv_g = (const float*)d_in[2];
    const float* kv_b = (const float*)d_in[3];
    const float* kv_m = (const float*)d_in[4];
    const float* kv_v = (const float*)d_in[5];
    const float* q_w  = (const float*)d_in[6];
    const float* q_g  = (const float*)d_in[7];
    const float* q_b  = (const float*)d_in[8];
    const float* q_m  = (const float*)d_in[9];
    const float* q_v  = (const float*)d_in[10];
    const float* pr_w = (const float*)d_in[11];
    const float* pr_g = (const float*)d_in[12];
    const float* pr_b = (const float*)d_in[13];
    const float* pr_m = (const float*)d_in[14];
    const float* pr_v = (const float*)d_in[15];
    const float* ab   = (const float*)d_in[16];
    const int*  idxs  = (const int*)d_in[17];
    const int n_off = in_sizes[16] / NH;

    char* ws = (char*)d_ws;
    size_t off = 0;
    auto alloc = [&](size_t bytes)->char*{
        char* p = ws + off; off += (bytes + 255) & ~(size_t)255; return p;
    };
    U16*   x_bf   = (U16*)  alloc((size_t)BSZ*NTOK*INDIM*2);   // 38.5 MB
    U16*   kvw_bf = (U16*)  alloc((size_t)KVH*INDIM*2);
    U16*   qw_bf  = (U16*)  alloc((size_t)INDIM*INDIM*2);
    U16*   prw_bf = (U16*)  alloc((size_t)OUTD*DHD*2);
    float* s_kv   = (float*)alloc(KVH*4);
    float* b_kv   = (float*)alloc(KVH*4);
    float* s_q    = (float*)alloc(INDIM*4);
    float* b_q    = (float*)alloc(INDIM*4);
    float* s_pr   = (float*)alloc(OUTD*4);
    float* b_pr   = (float*)alloc(OUTD*4);
    float* biasf  = (float*)alloc(((size_t)NH*NQ*NTOK + 256)*4);  // +pad for f4 tail reads
    U16*   a_out  = (U16*)  alloc((size_t)BSZ*NQ*DHD*2);       // 19.3 MB
    if (off > ws_size) return;  // insufficient workspace: fail visibly (no OOB writes)

    // prep (3 launches)
    {
        int n8 = BSZ*NTOK*INDIM/8;
        k_cast8<<<(n8+255)/256, 256, 0, stream>>>(x, x_bf, n8);
    }
    k_castw<<<(W1C+W2C+W3C+255)/256, 256, 0, stream>>>(kv_w, q_w, pr_w, kvw_bf, qw_bf, prw_bf);
    k_misc<<<BIAS_BLK+BN_BLK, 256, 0, stream>>>(
        ab, idxs, n_off,
        kv_g, kv_b, kv_m, kv_v, q_g, q_b, q_m, q_v, pr_g, pr_b, pr_m, pr_v,
        s_kv, b_kv, s_q, b_q, s_pr, b_pr, biasf);

    // fused kv-GEMM + q-GEMM + attention + hard_swish (XCD-swizzled)
    k_fused<<<BSZ*NH, 256, 0, stream>>>(x_bf, kvw_bf, qw_bf, s_kv, b_kv, s_q, b_q,
                                        biasf, a_out);

    // proj GEMM: (12544 x 512 x 768) -> f32 out (XCD-swizzled 1-D grid)
    k_proj<<<392, 256, 0, stream>>>(a_out, prw_bf, s_pr, b_pr, (float*)d_out);
}

// Round 8
// 200.380 us; speedup vs baseline: 1.5305x; 1.0780x over previous
//
#include <hip/hip_runtime.h>
#include <hip/hip_bf16.h>
#include <math.h>

typedef unsigned short U16;
typedef unsigned int U32;
typedef __attribute__((ext_vector_type(8))) short bf8;        // 8 x bf16 (MFMA A/B frag)
typedef __attribute__((ext_vector_type(4))) float f4;         // MFMA C/D frag
typedef __attribute__((ext_vector_type(4))) unsigned short u16x4;

#define AS1 __attribute__((address_space(1)))
#define AS3 __attribute__((address_space(3)))

// ---- constants ----
#define BSZ   256
#define NTOK  196
#define NQ    49
#define INDIM 384
#define OUTD  512
#define NH    12
#define DV    64
#define DHD   768
#define KVH   1152
#define NPADR 224      // padded token rows (196 real + 28 zero)

__device__ inline U16 f2bf(float f){
    __hip_bfloat16 h = __float2bfloat16(f);
    return *(U16*)&h;
}
__device__ inline f4 f4zero(){ f4 z; z[0]=0.f; z[1]=0.f; z[2]=0.f; z[3]=0.f; return z; }
__device__ inline bf8 bf8zero(){ bf8 v;
#pragma unroll
    for (int j=0;j<8;++j) v[j]=0; return v; }

// ---------------- prep kernels ----------------
// cast x -> x_bf padded [256][224][384] (rows 196..223 = 0)
__global__ void k_cast8p(const float* __restrict__ in, U16* __restrict__ out, int n8){
    int i = blockIdx.x*256 + threadIdx.x;
    if (i >= n8) return;
    int rall = i / 48;         // 48 = 384/8
    int c8   = i - rall*48;
    int b    = rall / NPADR;
    int r    = rall - b*NPADR;
    U16 o[8];
    if (r < NTOK){
        const float* p = in + ((size_t)(b*NTOK + r))*INDIM + c8*8;
#pragma unroll
        for (int j=0;j<8;++j) o[j] = f2bf(p[j]);
    } else {
#pragma unroll
        for (int j=0;j<8;++j) o[j] = 0;
    }
    *(bf8*)(out + (size_t)i*8) = *(const bf8*)o;
}

// subsampled xs cast: [256][49][384]
__global__ void k_castxs(const float* __restrict__ x, U16* __restrict__ out, int n8){
    int i = blockIdx.x*256 + threadIdx.x;
    if (i >= n8) return;
    int row = i / 48;
    int c8  = i - row*48;
    int b   = row / 49;
    int q   = row - b*49;
    int r_  = q / 7, c_ = q - r_*7;
    const float* p = x + ((size_t)(b*NTOK + 28*r_ + 2*c_))*INDIM + c8*8;
    U16 o[8];
#pragma unroll
    for (int j=0;j<8;++j) o[j] = f2bf(p[j]);
    *(bf8*)(out + (size_t)i*8) = *(const bf8*)o;
}

// all three weight casts in one launch
#define W1C (KVH*INDIM/8)            // 55296
#define W2C (INDIM*INDIM/8)          // 18432
#define W3C (OUTD*DHD/8)             // 49152
__global__ void k_castw(const float* __restrict__ w1, const float* __restrict__ w2,
                        const float* __restrict__ w3, U16* __restrict__ o1,
                        U16* __restrict__ o2, U16* __restrict__ o3){
    int i = blockIdx.x*256 + threadIdx.x;
    const float* p; U16* o;
    if (i < W1C){ p = w1 + (size_t)i*8; o = o1 + (size_t)i*8; }
    else if (i < W1C+W2C){ int k=i-W1C; p = w2 + (size_t)k*8; o = o2 + (size_t)k*8; }
    else if (i < W1C+W2C+W3C){ int k=i-W1C-W2C; p = w3 + (size_t)k*8; o = o3 + (size_t)k*8; }
    else return;
    U16 t[8];
#pragma unroll
    for (int j=0;j<8;++j) t[j] = f2bf(p[j]);
    *(bf8*)o = *(const bf8*)t;
}

// bias expand + BN folds, one launch
#define BIAS_N   (NH*NQ*NTOK)        // 115248
#define BIAS_BLK ((BIAS_N+255)/256)  // 451
#define BN_BLK   ((KVH+INDIM+OUTD)/256)  // 8
__global__ void k_misc(const float* __restrict__ ab, const int* __restrict__ idxs, int n_off,
                       const float* __restrict__ g1, const float* __restrict__ b1,
                       const float* __restrict__ m1, const float* __restrict__ v1,
                       const float* __restrict__ g2, const float* __restrict__ b2,
                       const float* __restrict__ m2, const float* __restrict__ v2,
                       const float* __restrict__ g3, const float* __restrict__ b3,
                       const float* __restrict__ m3, const float* __restrict__ v3,
                       float* __restrict__ s1, float* __restrict__ bo1,
                       float* __restrict__ s2, float* __restrict__ bo2,
                       float* __restrict__ s3, float* __restrict__ bo3,
                       float* __restrict__ bias_out){
    int blk = blockIdx.x;
    int tid = threadIdx.x;
    if (blk < BIAS_BLK){
        int i = blk*256 + tid;
        if (i < BIAS_N){
            int h = i / (NQ*NTOK);
            int qk = i - h*(NQ*NTOK);
            bias_out[i] = ab[h*n_off + idxs[qk]];
        }
    } else {
        int i = (blk-BIAS_BLK)*256 + tid;
        const float *g,*b,*m,*v; float *so,*bo; int k;
        if (i < KVH){ g=g1;b=b1;m=m1;v=v1;so=s1;bo=bo1;k=i; }
        else if (i < KVH+INDIM){ g=g2;b=b2;m=m2;v=v2;so=s2;bo=bo2;k=i-KVH; }
        else { g=g3;b=b3;m=m3;v=v3;so=s3;bo=bo3;k=i-KVH-INDIM; }
        float s = g[k] / sqrtf(v[k] + 1e-5f);
        so[k] = s;
        bo[k] = b[k] - m[k]*s;
    }
}

// ---------------- fused kv-GEMM + attention: 2 heads per 512-thread block ----------------
// GEMM: C[224 rows][192 cols = head0(k32|v64) | head1(k32|v64)], BK=64, 6 K-steps.
// One A staging serves both heads. Counted vmcnt. Then per-head attention (4 waves each).
// LDS map (u16, 57344 total = 114,688 B):
//   staging: A0 [0,14336) A1 [14336,28672) B0 [28672,40960) B1 [40960,53248)
//   post-GEMM per head t: base Ht = t*28672:
//     KL_t [Ht, Ht+7168)        [4 dch][224 n][8]
//     VL_t [Ht+7168, Ht+21504)  [28 nch][64 d][8]
//     plds_t rows<32 at [Ht+21504, Ht+28672), rows>=32 alias KL_t (dead after QK barrier)
__global__ __launch_bounds__(512,2) void k_fused(
    const U16* __restrict__ xbf, const U16* __restrict__ kvw, const U16* __restrict__ qo_,
    const float* __restrict__ skv, const float* __restrict__ bkv,
    const float* __restrict__ biasf, U16* __restrict__ aout)
{
    __shared__ U16 smem[57344];   // 114,688 B -> 1 block/CU, 8 waves
    const int hw = blockIdx.x;
    const int pair = (hw & 7)*192 + (hw >> 3);   // bijective XCD swizzle (1536 = 8*192)
    const int b = pair / 6, hp = pair - b*6;
    const int tid = threadIdx.x, lane = tid & 63, w = tid >> 6;
    const int wm = w & 1, wc = w >> 1;
    const int l15 = lane & 15, oct = lane >> 4;

    U16* Ab[2] = { smem + 0,     smem + 14336 };
    U16* Bb[2] = { smem + 28672, smem + 40960 };

    // A: 224 rows x 8 chunks = 1792 slots (chunk-major: slot = ch*224 + row)
    U32 aoff[4];
#pragma unroll
    for (int c=0;c<3;++c){
        int s = c*512 + tid;
        int ach = s / NPADR, ar = s - ach*NPADR;
        aoff[c] = (U32)(b*NPADR + ar)*INDIM + ach*8;
    }
    if (tid >= 256){
        int s = 1280 + tid;                        // slots 1536..1791
        int ach = s / NPADR, ar = s - ach*NPADR;
        aoff[3] = (U32)(b*NPADR + ar)*INDIM + ach*8;
    }
    // B: 192 rows (= kvw rows hp*192 .. +192) x 8 chunks = 1536 slots
    U32 boff[3];
#pragma unroll
    for (int c=0;c<3;++c){
        int s = c*512 + tid;
        int bch = s / 192, br = s - bch*192;
        boff[c] = (U32)(hp*192 + br)*INDIM + bch*8;
    }

    f4 acc[7][3];
#pragma unroll
    for (int i=0;i<7;++i)
#pragma unroll
        for (int j=0;j<3;++j) acc[i][j] = f4zero();

#define STAGE(buf, kb) do{ \
    _Pragma("unroll") \
    for (int c=0;c<3;++c) \
        __builtin_amdgcn_global_load_lds((const AS1 U32*)(xbf + aoff[c] + (kb)), \
            (AS3 U32*)(Ab[buf] + (c*512+tid)*8), 16, 0, 0); \
    if (tid >= 256) \
        __builtin_amdgcn_global_load_lds((const AS1 U32*)(xbf + aoff[3] + (kb)), \
            (AS3 U32*)(Ab[buf] + (1280+tid)*8), 16, 0, 0); \
    _Pragma("unroll") \
    for (int c=0;c<3;++c) \
        __builtin_amdgcn_global_load_lds((const AS1 U32*)(kvw + boff[c] + (kb)), \
            (AS3 U32*)(Bb[buf] + (c*512+tid)*8), 16, 0, 0); \
}while(0)

    STAGE(0, 0);

#pragma unroll
    for (int kt=0; kt<6; ++kt){
        const int cur = kt & 1;
        if (kt < 5){
            STAGE(cur^1, (kt+1)*64);
            if (w < 4) asm volatile("s_waitcnt vmcnt(6)" ::: "memory");
            else       asm volatile("s_waitcnt vmcnt(7)" ::: "memory");
        } else {
            asm volatile("s_waitcnt vmcnt(0)" ::: "memory");
        }
        __builtin_amdgcn_sched_barrier(0);
        __builtin_amdgcn_s_barrier();
        __builtin_amdgcn_sched_barrier(0);

#pragma unroll
        for (int kk=0;kk<2;++kk){
            bf8 af[7], bfr[3];
#pragma unroll
            for (int i=0;i<7;++i)
                af[i]  = *(const bf8*)(Ab[cur] + ((kk*4+oct)*NPADR + wm*112 + i*16 + l15)*8);
#pragma unroll
            for (int j=0;j<3;++j)
                bfr[j] = *(const bf8*)(Bb[cur] + ((kk*4+oct)*192 + wc*48 + j*16 + l15)*8);
            __builtin_amdgcn_s_setprio(1);
#pragma unroll
            for (int i=0;i<7;++i)
#pragma unroll
                for (int j=0;j<3;++j)
                    acc[i][j] = __builtin_amdgcn_mfma_f32_16x16x32_bf16(af[i], bfr[j], acc[i][j], 0, 0, 0);
            __builtin_amdgcn_s_setprio(0);
        }
        __builtin_amdgcn_sched_barrier(0);
        __builtin_amdgcn_s_barrier();
        __builtin_amdgcn_sched_barrier(0);
    }
#undef STAGE

    // ---- epilogue: BN fold, scatter acc -> KL/VL of this wave's head ----
    const int hT = wc >> 1;              // head half this wave computes
    const int hG = hp*2 + hT;            // global head
    U16* KLt = smem + hT*28672;
    U16* VLt = KLt + 7168;
#pragma unroll
    for (int j=0;j<3;++j){
        const int cc = (wc&1)*48 + j*16 + l15;     // [0,96)
        const float sc = skv[hG*96 + cc];
        const float bi = bkv[hG*96 + cc];
#pragma unroll
        for (int i=0;i<7;++i){
            const int n0 = wm*112 + i*16 + oct*4;  // [0,224)
            if (cc < 32){
#pragma unroll
                for (int r=0;r<4;++r)
                    KLt[((cc>>3)*NPADR + n0 + r)*8 + (cc&7)] = f2bf(acc[i][j][r]*sc + bi);
            } else {
                const int dv = cc - 32;
                u16x4 pk;
#pragma unroll
                for (int r=0;r<4;++r) pk[r] = f2bf(acc[i][j][r]*sc + bi);
                *(u16x4*)(VLt + ((n0>>3)*64 + dv)*8 + (oct&1)*4) = pk;
            }
        }
    }
    __syncthreads();   // K/V visible to all waves of the head

    // ---- attention: head t = w>>2; 4 waves per head, each wave 16 q-cols ----
    const int t = w >> 2;
    const int h = hp*2 + t;
    U16* KLa = smem + t*28672;
    U16* VLa = KLa + 7168;
    const int qg = (w&3)*16 + l15;
    bf8 qf = bf8zero();
    if (qg < NQ) qf = *(const bf8*)(qo_ + ((size_t)(b*NQ + qg))*INDIM + h*32 + oct*8);

    f4 sacc[14];
#pragma unroll
    for (int mt=0;mt<14;++mt) sacc[mt] = f4zero();
#pragma unroll
    for (int mt=0;mt<14;++mt){
        const bf8 kf = *(const bf8*)(KLa + (oct*NPADR + mt*16 + l15)*8);
        sacc[mt] = __builtin_amdgcn_mfma_f32_16x16x32_bf16(kf, qf, sacc[mt], 0, 0, 0);
    }

    const float scale = 0.17677669529663689f;   // 1/sqrt(32)
    float mx = -1e30f;
#pragma unroll
    for (int mt=0;mt<14;++mt){
        const int n0 = mt*16 + oct*4;
        f4 bi4 = f4zero();
        if (qg < NQ && n0 < NTOK) bi4 = *(const f4*)(biasf + ((size_t)h*NQ + qg)*NTOK + n0);
#pragma unroll
        for (int r=0;r<4;++r){
            float s = (n0 + r < NTOK) ? sacc[mt][r]*scale + bi4[r] : -1e30f;
            sacc[mt][r] = s;
            mx = fmaxf(mx, s);
        }
    }
    mx = fmaxf(mx, __shfl_xor(mx, 16));
    mx = fmaxf(mx, __shfl_xor(mx, 32));

    float sum = 0.f;
#pragma unroll
    for (int mt=0;mt<14;++mt){
#pragma unroll
        for (int r=0;r<4;++r){
            float p = (mt*16 + oct*4 + r < NTOK) ? __expf(sacc[mt][r] - mx) : 0.f;
            sacc[mt][r] = p;
            sum += p;
        }
    }
    sum += __shfl_xor(sum, 16);
    sum += __shfl_xor(sum, 32);
    const float inv = 1.f / sum;

    __syncthreads();   // all QK^T reads of KL done -> plds may alias KL

    // P -> plds (bf16): row = q, cols n; split region, XOR-swizzled 8-u16 block index
    const int prow = (w&3)*16 + l15;
    const int pbase = t*28672 + ((prow < 32) ? (21504 + prow*NPADR) : ((prow-32)*NPADR));
    const int psw = prow & 3;
#pragma unroll
    for (int mt=0;mt<14;++mt){
        u16x4 pk;
#pragma unroll
        for (int r=0;r<4;++r) pk[r] = f2bf(sacc[mt][r]*inv);
        const int blk = (mt*2 + (oct>>1)) ^ psw;
        *(u16x4*)(smem + pbase + blk*8 + (oct&1)*4) = pk;
    }
    // own-wave rows only -> no barrier needed before PV

    // PV: out(q,d) = P(q,n) @ v(n,d)
    f4 pacc[4];
#pragma unroll
    for (int dt=0;dt<4;++dt) pacc[dt] = f4zero();
#pragma unroll
    for (int kt=0;kt<7;++kt){
        const bf8 pa = *(const bf8*)(smem + pbase + ((kt*4 + oct) ^ psw)*8);
#pragma unroll
        for (int dt=0;dt<4;++dt){
            const bf8 vf = *(const bf8*)(VLa + ((kt*4 + oct)*64 + dt*16 + l15)*8);
            pacc[dt] = __builtin_amdgcn_mfma_f32_16x16x32_bf16(pa, vf, pacc[dt], 0, 0, 0);
        }
    }

    // hard_swish, store bf16 (b, q, h*64+d)
#pragma unroll
    for (int dt=0;dt<4;++dt){
#pragma unroll
        for (int r=0;r<4;++r){
            const int qo2 = (w&3)*16 + oct*4 + r;
            if (qo2 < NQ){
                const int d = dt*16 + l15;
                float v = pacc[dt][r];
                float tt = fminf(fmaxf(v + 3.f, 0.f), 6.f);
                aout[((size_t)(b*NQ + qo2))*DHD + h*DV + d] = f2bf(v * tt * (1.f/6.f));
            }
        }
    }
}

// ---------------- q GEMM 128x128x64 (12544 x 384 x 384), bf16 out ----------------
__global__ __launch_bounds__(256,2) void k_qgemm(
    const U16* __restrict__ A, const U16* __restrict__ Bw,
    const float* __restrict__ s_arr, const float* __restrict__ b_arr,
    U16* __restrict__ o16)
{
    __shared__ U16 smem[32768];
    U16* Ab[2] = { smem,          smem + 8192 };
    U16* Bb[2] = { smem + 16384,  smem + 24576 };
    const int gn0 = blockIdx.x * 128;
    const int gm0 = blockIdx.y * 128;
    const int tid  = threadIdx.x;
    const int lane = tid & 63;
    const int w    = tid >> 6;
    const int wm   = w >> 1, wn = w & 1;
    const int l15  = lane & 15, oct = lane >> 4;

    f4 acc[4][4];
#pragma unroll
    for (int i=0;i<4;++i)
#pragma unroll
        for (int j=0;j<4;++j) acc[i][j] = f4zero();

    size_t aoff[4], boff[4];
#pragma unroll
    for (int c=0;c<4;++c){
        int slot = c*256 + tid;
        int row = slot & 127, ch = slot >> 7;
        aoff[c] = (size_t)(gm0 + row)*INDIM + ch*8;
        boff[c] = (size_t)(gn0 + row)*INDIM + ch*8;
    }

#pragma unroll
    for (int c=0;c<4;++c){
        __builtin_amdgcn_global_load_lds((const AS1 U32*)(A + aoff[c]),
            (AS3 U32*)(Ab[0] + (c*256+tid)*8), 16, 0, 0);
        __builtin_amdgcn_global_load_lds((const AS1 U32*)(Bw + boff[c]),
            (AS3 U32*)(Bb[0] + (c*256+tid)*8), 16, 0, 0);
    }

#pragma unroll
    for (int kt=0; kt<6; ++kt){
        const int cur = kt & 1;
        if (kt+1 < 6){
            const int kb = (kt+1)*64;
#pragma unroll
            for (int c=0;c<4;++c){
                __builtin_amdgcn_global_load_lds((const AS1 U32*)(A + aoff[c] + kb),
                    (AS3 U32*)(Ab[cur^1] + (c*256+tid)*8), 16, 0, 0);
                __builtin_amdgcn_global_load_lds((const AS1 U32*)(Bw + boff[c] + kb),
                    (AS3 U32*)(Bb[cur^1] + (c*256+tid)*8), 16, 0, 0);
            }
            asm volatile("s_waitcnt vmcnt(8)" ::: "memory");
        } else {
            asm volatile("s_waitcnt vmcnt(0)" ::: "memory");
        }
        __builtin_amdgcn_sched_barrier(0);
        __builtin_amdgcn_s_barrier();
        __builtin_amdgcn_sched_barrier(0);

#pragma unroll
        for (int kk=0;kk<2;++kk){
            bf8 af[4], bfr[4];
#pragma unroll
            for (int i=0;i<4;++i)
                af[i]  = *(const bf8*)(Ab[cur] + ((kk*4+oct)*128 + wm*64 + i*16 + l15)*8);
#pragma unroll
            for (int j=0;j<4;++j)
                bfr[j] = *(const bf8*)(Bb[cur] + ((kk*4+oct)*128 + wn*64 + j*16 + l15)*8);
            __builtin_amdgcn_s_setprio(1);
#pragma unroll
            for (int i=0;i<4;++i)
#pragma unroll
                for (int j=0;j<4;++j)
                    acc[i][j] = __builtin_amdgcn_mfma_f32_16x16x32_bf16(af[i], bfr[j], acc[i][j], 0, 0, 0);
            __builtin_amdgcn_s_setprio(0);
        }
        __builtin_amdgcn_sched_barrier(0);
        __builtin_amdgcn_s_barrier();
        __builtin_amdgcn_sched_barrier(0);
    }

#pragma unroll
    for (int j=0;j<4;++j){
        const int col = gn0 + wn*64 + j*16 + l15;
        const float sc = s_arr[col];
        const float bi = b_arr[col];
#pragma unroll
        for (int i=0;i<4;++i){
            const int row0 = gm0 + wm*64 + i*16 + oct*4;
#pragma unroll
            for (int r=0;r<4;++r)
                o16[(size_t)(row0+r)*INDIM + col] = f2bf(acc[i][j][r]*sc + bi);
        }
    }
}

// ---------------- proj GEMM 128x128x64, counted-vmcnt double buffer ----------------
__global__ __launch_bounds__(256,2) void k_proj(
    const U16* __restrict__ A, const U16* __restrict__ Bw,
    const float* __restrict__ s_arr, const float* __restrict__ b_arr,
    float* __restrict__ o32)
{
    __shared__ U16 smem[32768];
    U16* Ab[2] = { smem,          smem + 8192 };
    U16* Bb[2] = { smem + 16384,  smem + 24576 };
    const int l   = (blockIdx.x & 7)*49 + (blockIdx.x >> 3);   // bijective (392 = 8*49)
    const int gn0 = (l & 3) * 128;
    const int gm0 = (l >> 2) * 128;
    const int tid  = threadIdx.x;
    const int lane = tid & 63;
    const int w    = tid >> 6;
    const int wm   = w >> 1, wn = w & 1;
    const int l15  = lane & 15, oct = lane >> 4;

    f4 acc[4][4];
#pragma unroll
    for (int i=0;i<4;++i)
#pragma unroll
        for (int j=0;j<4;++j) acc[i][j] = f4zero();

    size_t aoff[4], boff[4];
#pragma unroll
    for (int c=0;c<4;++c){
        int slot = c*256 + tid;
        int row = slot & 127, ch = slot >> 7;
        aoff[c] = (size_t)(gm0 + row)*DHD + ch*8;
        boff[c] = (size_t)(gn0 + row)*DHD + ch*8;
    }

#pragma unroll
    for (int c=0;c<4;++c){
        __builtin_amdgcn_global_load_lds((const AS1 U32*)(A + aoff[c]),
            (AS3 U32*)(Ab[0] + (c*256+tid)*8), 16, 0, 0);
        __builtin_amdgcn_global_load_lds((const AS1 U32*)(Bw + boff[c]),
            (AS3 U32*)(Bb[0] + (c*256+tid)*8), 16, 0, 0);
    }

#pragma unroll
    for (int kt=0; kt<12; ++kt){
        const int cur = kt & 1;
        if (kt+1 < 12){
            const int kb = (kt+1)*64;
#pragma unroll
            for (int c=0;c<4;++c){
                __builtin_amdgcn_global_load_lds((const AS1 U32*)(A + aoff[c] + kb),
                    (AS3 U32*)(Ab[cur^1] + (c*256+tid)*8), 16, 0, 0);
                __builtin_amdgcn_global_load_lds((const AS1 U32*)(Bw + boff[c] + kb),
                    (AS3 U32*)(Bb[cur^1] + (c*256+tid)*8), 16, 0, 0);
            }
            asm volatile("s_waitcnt vmcnt(8)" ::: "memory");
        } else {
            asm volatile("s_waitcnt vmcnt(0)" ::: "memory");
        }
        __builtin_amdgcn_sched_barrier(0);
        __builtin_amdgcn_s_barrier();
        __builtin_amdgcn_sched_barrier(0);

#pragma unroll
        for (int kk=0;kk<2;++kk){
            bf8 af[4], bfr[4];
#pragma unroll
            for (int i=0;i<4;++i)
                af[i]  = *(const bf8*)(Ab[cur] + ((kk*4+oct)*128 + wm*64 + i*16 + l15)*8);
#pragma unroll
            for (int j=0;j<4;++j)
                bfr[j] = *(const bf8*)(Bb[cur] + ((kk*4+oct)*128 + wn*64 + j*16 + l15)*8);
            __builtin_amdgcn_s_setprio(1);
#pragma unroll
            for (int i=0;i<4;++i)
#pragma unroll
                for (int j=0;j<4;++j)
                    acc[i][j] = __builtin_amdgcn_mfma_f32_16x16x32_bf16(af[i], bfr[j], acc[i][j], 0, 0, 0);
            __builtin_amdgcn_s_setprio(0);
        }
        __builtin_amdgcn_sched_barrier(0);
        __builtin_amdgcn_s_barrier();
        __builtin_amdgcn_sched_barrier(0);
    }

#pragma unroll
    for (int j=0;j<4;++j){
        const int col = gn0 + wn*64 + j*16 + l15;
        const float sc = s_arr[col];
        const float bi = b_arr[col];
#pragma unroll
        for (int i=0;i<4;++i){
            const int row0 = gm0 + wm*64 + i*16 + oct*4;
#pragma unroll
            for (int r=0;r<4;++r)
                o32[(size_t)(row0+r)*OUTD + col] = acc[i][j][r]*sc + bi;
        }
    }
}

// ---------------- launch ----------------
extern "C" void kernel_launch(void* const* d_in, const int* in_sizes, int n_in,
                              void* d_out, int out_size, void* d_ws, size_t ws_size,
                              hipStream_t stream)
{
    const float* x    = (const float*)d_in[0];
    const float* kv_w = (const float*)d_in[1];
    const float* kv_g = (const float*)d_in[2];
    const float* kv_b = (const float*)d_in[3];
    const float* kv_m = (const float*)d_in[4];
    const float* kv_v = (const float*)d_in[5];
    const float* q_w  = (const float*)d_in[6];
    const float* q_g  = (const float*)d_in[7];
    const float* q_b  = (const float*)d_in[8];
    const float* q_m  = (const float*)d_in[9];
    const float* q_v  = (const float*)d_in[10];
    const float* pr_w = (const float*)d_in[11];
    const float* pr_g = (const float*)d_in[12];
    const float* pr_b = (const float*)d_in[13];
    const float* pr_m = (const float*)d_in[14];
    const float* pr_v = (const float*)d_in[15];
    const float* ab   = (const float*)d_in[16];
    const int*  idxs  = (const int*)d_in[17];
    const int n_off = in_sizes[16] / NH;

    char* ws = (char*)d_ws;
    size_t off = 0;
    auto alloc = [&](size_t bytes)->char*{
        char* p = ws + off; off += (bytes + 255) & ~(size_t)255; return p;
    };
    U16*   x_bf   = (U16*)  alloc((size_t)BSZ*NPADR*INDIM*2); // 44 MB (padded)
    U16*   xs_bf  = (U16*)  alloc((size_t)BSZ*NQ*INDIM*2);    // 9.6 MB
    U16*   kvw_bf = (U16*)  alloc((size_t)KVH*INDIM*2);
    U16*   qw_bf  = (U16*)  alloc((size_t)INDIM*INDIM*2);
    U16*   prw_bf = (U16*)  alloc((size_t)OUTD*DHD*2);
    float* s_kv   = (float*)alloc(KVH*4);
    float* b_kv   = (float*)alloc(KVH*4);
    float* s_q    = (float*)alloc(INDIM*4);
    float* b_q    = (float*)alloc(INDIM*4);
    float* s_pr   = (float*)alloc(OUTD*4);
    float* b_pr   = (float*)alloc(OUTD*4);
    float* biasf  = (float*)alloc(((size_t)NH*NQ*NTOK + 256)*4);  // +pad for f4 tail reads
    U16*   q_out  = (U16*)  alloc((size_t)BSZ*NQ*INDIM*2);    // 9.6 MB
    U16*   a_out  = (U16*)  alloc((size_t)BSZ*NQ*DHD*2);      // 19.3 MB
    if (off > ws_size) return;  // insufficient workspace: fail visibly (no OOB writes)

    // prep (4 launches)
    {
        int n8 = BSZ*NPADR*INDIM/8;
        k_cast8p<<<(n8+255)/256, 256, 0, stream>>>(x, x_bf, n8);
    }
    {
        int n8 = BSZ*NQ*INDIM/8;
        k_castxs<<<(n8+255)/256, 256, 0, stream>>>(x, xs_bf, n8);
    }
    k_castw<<<(W1C+W2C+W3C+255)/256, 256, 0, stream>>>(kv_w, q_w, pr_w, kvw_bf, qw_bf, prw_bf);
    k_misc<<<BIAS_BLK+BN_BLK, 256, 0, stream>>>(
        ab, idxs, n_off,
        kv_g, kv_b, kv_m, kv_v, q_g, q_b, q_m, q_v, pr_g, pr_b, pr_m, pr_v,
        s_kv, b_kv, s_q, b_q, s_pr, b_pr, biasf);

    // q GEMM: (12544 x 384 x 384) -> bf16 row-major
    {
        dim3 g(INDIM/128, BSZ*NQ/128);
        k_qgemm<<<g, 256, 0, stream>>>(xs_bf, qw_bf, s_q, b_q, q_out);
    }
    // fused kv-GEMM + attention + hard_swish (2 heads/block, XCD-swizzled)
    k_fused<<<BSZ*NH/2, 512, 0, stream>>>(x_bf, kvw_bf, q_out, s_kv, b_kv, biasf, a_out);
    // proj GEMM: (12544 x 512 x 768) -> f32 out (XCD-swizzled 1-D grid)
    k_proj<<<392, 256, 0, stream>>>(a_out, prw_bf, s_pr, b_pr, (float*)d_out);
}

// Round 9
// 197.135 us; speedup vs baseline: 1.5557x; 1.0165x over previous
//
#include <hip/hip_runtime.h>
#include <hip/hip_bf16.h>
#include <math.h>

typedef unsigned short U16;
typedef unsigned int U32;
typedef __attribute__((ext_vector_type(8))) short bf8;        // 8 x bf16 (MFMA A/B frag)
typedef __attribute__((ext_vector_type(4))) float f4;         // MFMA C/D frag
typedef __attribute__((ext_vector_type(4))) unsigned short u16x4;

#define AS1 __attribute__((address_space(1)))
#define AS3 __attribute__((address_space(3)))

// ---- constants ----
#define BSZ   256
#define NTOK  196
#define NQ    49
#define INDIM 384
#define OUTD  512
#define NH    12
#define DV    64
#define DHD   768
#define KVH   1152
#define NPADR 224      // padded token rows (196 real + 28 zero)

__device__ inline U16 f2bf(float f){
    __hip_bfloat16 h = __float2bfloat16(f);
    return *(U16*)&h;
}
__device__ inline f4 f4zero(){ f4 z; z[0]=0.f; z[1]=0.f; z[2]=0.f; z[3]=0.f; return z; }
__device__ inline bf8 bf8zero(){ bf8 v;
#pragma unroll
    for (int j=0;j<8;++j) v[j]=0; return v; }

// ---------------- prep kernels ----------------
// cast x -> x_bf padded [256][224][384] (rows 196..223 = 0)
__global__ void k_cast8p(const float* __restrict__ in, U16* __restrict__ out, int n8){
    int i = blockIdx.x*256 + threadIdx.x;
    if (i >= n8) return;
    int rall = i / 48;         // 48 = 384/8
    int c8   = i - rall*48;
    int b    = rall / NPADR;
    int r    = rall - b*NPADR;
    U16 o[8];
    if (r < NTOK){
        const float* p = in + ((size_t)(b*NTOK + r))*INDIM + c8*8;
#pragma unroll
        for (int j=0;j<8;++j) o[j] = f2bf(p[j]);
    } else {
#pragma unroll
        for (int j=0;j<8;++j) o[j] = 0;
    }
    *(bf8*)(out + (size_t)i*8) = *(const bf8*)o;
}

// subsampled xs cast: [256][49][384]
__global__ void k_castxs(const float* __restrict__ x, U16* __restrict__ out, int n8){
    int i = blockIdx.x*256 + threadIdx.x;
    if (i >= n8) return;
    int row = i / 48;
    int c8  = i - row*48;
    int b   = row / 49;
    int q   = row - b*49;
    int r_  = q / 7, c_ = q - r_*7;
    const float* p = x + ((size_t)(b*NTOK + 28*r_ + 2*c_))*INDIM + c8*8;
    U16 o[8];
#pragma unroll
    for (int j=0;j<8;++j) o[j] = f2bf(p[j]);
    *(bf8*)(out + (size_t)i*8) = *(const bf8*)o;
}

// all three weight casts in one launch
#define W1C (KVH*INDIM/8)            // 55296
#define W2C (INDIM*INDIM/8)          // 18432
#define W3C (OUTD*DHD/8)             // 49152
__global__ void k_castw(const float* __restrict__ w1, const float* __restrict__ w2,
                        const float* __restrict__ w3, U16* __restrict__ o1,
                        U16* __restrict__ o2, U16* __restrict__ o3){
    int i = blockIdx.x*256 + threadIdx.x;
    const float* p; U16* o;
    if (i < W1C){ p = w1 + (size_t)i*8; o = o1 + (size_t)i*8; }
    else if (i < W1C+W2C){ int k=i-W1C; p = w2 + (size_t)k*8; o = o2 + (size_t)k*8; }
    else if (i < W1C+W2C+W3C){ int k=i-W1C-W2C; p = w3 + (size_t)k*8; o = o3 + (size_t)k*8; }
    else return;
    U16 t[8];
#pragma unroll
    for (int j=0;j<8;++j) t[j] = f2bf(p[j]);
    *(bf8*)o = *(const bf8*)t;
}

// bias expand + BN folds, one launch
#define BIAS_N   (NH*NQ*NTOK)        // 115248
#define BIAS_BLK ((BIAS_N+255)/256)  // 451
#define BN_BLK   ((KVH+INDIM+OUTD)/256)  // 8
__global__ void k_misc(const float* __restrict__ ab, const int* __restrict__ idxs, int n_off,
                       const float* __restrict__ g1, const float* __restrict__ b1,
                       const float* __restrict__ m1, const float* __restrict__ v1,
                       const float* __restrict__ g2, const float* __restrict__ b2,
                       const float* __restrict__ m2, const float* __restrict__ v2,
                       const float* __restrict__ g3, const float* __restrict__ b3,
                       const float* __restrict__ m3, const float* __restrict__ v3,
                       float* __restrict__ s1, float* __restrict__ bo1,
                       float* __restrict__ s2, float* __restrict__ bo2,
                       float* __restrict__ s3, float* __restrict__ bo3,
                       float* __restrict__ bias_out){
    int blk = blockIdx.x;
    int tid = threadIdx.x;
    if (blk < BIAS_BLK){
        int i = blk*256 + tid;
        if (i < BIAS_N){
            int h = i / (NQ*NTOK);
            int qk = i - h*(NQ*NTOK);
            bias_out[i] = ab[h*n_off + idxs[qk]];
        }
    } else {
        int i = (blk-BIAS_BLK)*256 + tid;
        const float *g,*b,*m,*v; float *so,*bo; int k;
        if (i < KVH){ g=g1;b=b1;m=m1;v=v1;so=s1;bo=bo1;k=i; }
        else if (i < KVH+INDIM){ g=g2;b=b2;m=m2;v=v2;so=s2;bo=bo2;k=i-KVH; }
        else { g=g3;b=b3;m=m3;v=v3;so=s3;bo=bo3;k=i-KVH-INDIM; }
        float s = g[k] / sqrtf(v[k] + 1e-5f);
        so[k] = s;
        bo[k] = b[k] - m[k]*s;
    }
}

// ---------------- fused kv-GEMM + attention: 1 head per 256-thread block ----------------
// GEMM: C[224 rows][96 cols = k(32)|v(64)], BK=64, 6 K-steps, counted vmcnt(10).
// LDS 40960 u16 = 81,920 B exactly -> 2 blocks/CU (independent barriers = pipe overlap).
//   staging: A0 [0,14336) A1 [14336,28672) B0 [28672,34816) B1 [34816,40960)
//   post-GEMM (aliases dead staging):
//     KL [0,7168):      [4 dch][224 n][8]
//     VL [7168,21504):  [28 nch][64 d][8]
//     PL [21504,35840): [64 q][224 n] (8-u16 blocks, XOR-swizzled)
#define FA1 14336
#define FB0 28672
#define FB1 34816
#define VL  7168
#define PL  21504
__global__ __launch_bounds__(256,2) void k_fused(
    const U16* __restrict__ xbf, const U16* __restrict__ kvw, const U16* __restrict__ qo_,
    const float* __restrict__ skv, const float* __restrict__ bkv,
    const float* __restrict__ biasf, U16* __restrict__ aout)
{
    __shared__ U16 smem[40960];   // 81,920 B
    const int hw = blockIdx.x;
    const int bh = (hw & 7)*384 + (hw >> 3);   // bijective XCD swizzle (3072 = 8*384)
    const int b = bh / NH, h = bh - b*NH;
    const int tid = threadIdx.x, lane = tid & 63, w = tid >> 6;
    const int wm = w & 1, wn = w >> 1;
    const int l15 = lane & 15, oct = lane >> 4;

    U16* Ab[2] = { smem + 0,   smem + FA1 };
    U16* Bb[2] = { smem + FB0, smem + FB1 };

    // A: 224 rows x 8 chunks = 1792 slots; slot = ch*224 + row
    U32 aoff[7];
#pragma unroll
    for (int c=0;c<7;++c){
        int s = c*256 + tid;
        int ach = s / NPADR, ar = s - ach*NPADR;
        aoff[c] = (U32)(b*NPADR + ar)*INDIM + ach*8;
    }
    // B: 96 rows x 8 chunks = 768 slots; slot = ch*96 + row
    U32 boff[3];
#pragma unroll
    for (int c=0;c<3;++c){
        int s = c*256 + tid;
        int bch = s / 96, br = s - bch*96;
        boff[c] = (U32)(h*96 + br)*INDIM + bch*8;
    }

    f4 acc[7][3];
#pragma unroll
    for (int i=0;i<7;++i)
#pragma unroll
        for (int j=0;j<3;++j) acc[i][j] = f4zero();

#define STAGE(buf, kb) do{ \
    _Pragma("unroll") \
    for (int c=0;c<7;++c) \
        __builtin_amdgcn_global_load_lds((const AS1 U32*)(xbf + aoff[c] + (kb)), \
            (AS3 U32*)(Ab[buf] + (c*256+tid)*8), 16, 0, 0); \
    _Pragma("unroll") \
    for (int c=0;c<3;++c) \
        __builtin_amdgcn_global_load_lds((const AS1 U32*)(kvw + boff[c] + (kb)), \
            (AS3 U32*)(Bb[buf] + (c*256+tid)*8), 16, 0, 0); \
}while(0)

    STAGE(0, 0);

#pragma unroll
    for (int kt=0; kt<6; ++kt){
        const int cur = kt & 1;
        if (kt < 5){
            STAGE(cur^1, (kt+1)*64);
            asm volatile("s_waitcnt vmcnt(10)" ::: "memory");   // tile kt landed; kt+1 in flight
        } else {
            asm volatile("s_waitcnt vmcnt(0)" ::: "memory");
        }
        __builtin_amdgcn_sched_barrier(0);
        __builtin_amdgcn_s_barrier();
        __builtin_amdgcn_sched_barrier(0);

#pragma unroll
        for (int kk=0;kk<2;++kk){
            bf8 af[7], bfr[3];
#pragma unroll
            for (int i=0;i<7;++i)
                af[i]  = *(const bf8*)(Ab[cur] + ((kk*4+oct)*NPADR + wm*112 + i*16 + l15)*8);
#pragma unroll
            for (int j=0;j<3;++j)
                bfr[j] = *(const bf8*)(Bb[cur] + ((kk*4+oct)*96 + wn*48 + j*16 + l15)*8);
            __builtin_amdgcn_s_setprio(1);
#pragma unroll
            for (int i=0;i<7;++i)
#pragma unroll
                for (int j=0;j<3;++j)
                    acc[i][j] = __builtin_amdgcn_mfma_f32_16x16x32_bf16(af[i], bfr[j], acc[i][j], 0, 0, 0);
            __builtin_amdgcn_s_setprio(0);
        }
        __builtin_amdgcn_sched_barrier(0);
        __builtin_amdgcn_s_barrier();       // buf `cur` free for next iteration's staging
        __builtin_amdgcn_sched_barrier(0);
    }
#undef STAGE

    // ---- epilogue: BN fold, scatter acc -> KL/VL (alias dead staging) ----
#pragma unroll
    for (int j=0;j<3;++j){
        const int cc = wn*48 + j*16 + l15;     // [0,96)
        const float sc = skv[h*96 + cc];
        const float bi = bkv[h*96 + cc];
#pragma unroll
        for (int i=0;i<7;++i){
            const int n0 = wm*112 + i*16 + oct*4;  // [0,224)
            if (cc < 32){
#pragma unroll
                for (int r=0;r<4;++r)
                    smem[((cc>>3)*NPADR + n0 + r)*8 + (cc&7)] = f2bf(acc[i][j][r]*sc + bi);
            } else {
                const int dv = cc - 32;
                u16x4 pk;
#pragma unroll
                for (int r=0;r<4;++r) pk[r] = f2bf(acc[i][j][r]*sc + bi);
                *(u16x4*)(smem + VL + ((n0>>3)*64 + dv)*8 + (oct&1)*4) = pk;
            }
        }
    }
    __syncthreads();   // K/V visible to all waves

    // ---- attention: 4 waves, each wave 16 q-cols ----
    const int qg = w*16 + l15;
    bf8 qf = bf8zero();
    if (qg < NQ) qf = *(const bf8*)(qo_ + ((size_t)(b*NQ + qg))*INDIM + h*32 + oct*8);

    f4 sacc[14];
#pragma unroll
    for (int mt=0;mt<14;++mt) sacc[mt] = f4zero();
#pragma unroll
    for (int mt=0;mt<14;++mt){
        const bf8 kf = *(const bf8*)(smem + (oct*NPADR + mt*16 + l15)*8);
        sacc[mt] = __builtin_amdgcn_mfma_f32_16x16x32_bf16(kf, qf, sacc[mt], 0, 0, 0);
    }

    const float scale = 0.17677669529663689f;   // 1/sqrt(32)
    float mx = -1e30f;
#pragma unroll
    for (int mt=0;mt<14;++mt){
        const int n0 = mt*16 + oct*4;
        f4 bi4 = f4zero();
        if (qg < NQ && n0 < NTOK) bi4 = *(const f4*)(biasf + ((size_t)h*NQ + qg)*NTOK + n0);
#pragma unroll
        for (int r=0;r<4;++r){
            float s = (n0 + r < NTOK) ? sacc[mt][r]*scale + bi4[r] : -1e30f;
            sacc[mt][r] = s;
            mx = fmaxf(mx, s);
        }
    }
    mx = fmaxf(mx, __shfl_xor(mx, 16));
    mx = fmaxf(mx, __shfl_xor(mx, 32));

    float sum = 0.f;
#pragma unroll
    for (int mt=0;mt<14;++mt){
#pragma unroll
        for (int r=0;r<4;++r){
            float p = (mt*16 + oct*4 + r < NTOK) ? __expf(sacc[mt][r] - mx) : 0.f;
            sacc[mt][r] = p;
            sum += p;
        }
    }
    sum += __shfl_xor(sum, 16);
    sum += __shfl_xor(sum, 32);
    const float inv = 1.f / sum;

    // P -> PL (bf16): own-wave rows only; XOR-swizzled 8-u16 block index (no barrier needed:
    // PL does not alias KL/VL, and each wave reads back only its own rows)
    const int prow = w*16 + l15;
    const int pbase = PL + prow*NPADR;
    const int psw = prow & 3;
#pragma unroll
    for (int mt=0;mt<14;++mt){
        u16x4 pk;
#pragma unroll
        for (int r=0;r<4;++r) pk[r] = f2bf(sacc[mt][r]*inv);
        const int blk = (mt*2 + (oct>>1)) ^ psw;
        *(u16x4*)(smem + pbase + blk*8 + (oct&1)*4) = pk;
    }

    // PV: out(q,d) = P(q,n) @ v(n,d)
    f4 pacc[4];
#pragma unroll
    for (int dt=0;dt<4;++dt) pacc[dt] = f4zero();
#pragma unroll
    for (int kt=0;kt<7;++kt){
        const bf8 pa = *(const bf8*)(smem + pbase + ((kt*4 + oct) ^ psw)*8);
#pragma unroll
        for (int dt=0;dt<4;++dt){
            const bf8 vf = *(const bf8*)(smem + VL + ((kt*4 + oct)*64 + dt*16 + l15)*8);
            pacc[dt] = __builtin_amdgcn_mfma_f32_16x16x32_bf16(pa, vf, pacc[dt], 0, 0, 0);
        }
    }

    // hard_swish, store bf16 (b, q, h*64+d)
#pragma unroll
    for (int dt=0;dt<4;++dt){
#pragma unroll
        for (int r=0;r<4;++r){
            const int qo2 = w*16 + oct*4 + r;
            if (qo2 < NQ){
                const int d = dt*16 + l15;
                float v = pacc[dt][r];
                float tt = fminf(fmaxf(v + 3.f, 0.f), 6.f);
                aout[((size_t)(b*NQ + qo2))*DHD + h*DV + d] = f2bf(v * tt * (1.f/6.f));
            }
        }
    }
}

// ---------------- q GEMM 128x128x64 (12544 x 384 x 384), bf16 out ----------------
__global__ __launch_bounds__(256,2) void k_qgemm(
    const U16* __restrict__ A, const U16* __restrict__ Bw,
    const float* __restrict__ s_arr, const float* __restrict__ b_arr,
    U16* __restrict__ o16)
{
    __shared__ U16 smem[32768];
    U16* Ab[2] = { smem,          smem + 8192 };
    U16* Bb[2] = { smem + 16384,  smem + 24576 };
    const int gn0 = blockIdx.x * 128;
    const int gm0 = blockIdx.y * 128;
    const int tid  = threadIdx.x;
    const int lane = tid & 63;
    const int w    = tid >> 6;
    const int wm   = w >> 1, wn = w & 1;
    const int l15  = lane & 15, oct = lane >> 4;

    f4 acc[4][4];
#pragma unroll
    for (int i=0;i<4;++i)
#pragma unroll
        for (int j=0;j<4;++j) acc[i][j] = f4zero();

    size_t aoff[4], boff[4];
#pragma unroll
    for (int c=0;c<4;++c){
        int slot = c*256 + tid;
        int row = slot & 127, ch = slot >> 7;
        aoff[c] = (size_t)(gm0 + row)*INDIM + ch*8;
        boff[c] = (size_t)(gn0 + row)*INDIM + ch*8;
    }

#pragma unroll
    for (int c=0;c<4;++c){
        __builtin_amdgcn_global_load_lds((const AS1 U32*)(A + aoff[c]),
            (AS3 U32*)(Ab[0] + (c*256+tid)*8), 16, 0, 0);
        __builtin_amdgcn_global_load_lds((const AS1 U32*)(Bw + boff[c]),
            (AS3 U32*)(Bb[0] + (c*256+tid)*8), 16, 0, 0);
    }

#pragma unroll
    for (int kt=0; kt<6; ++kt){
        const int cur = kt & 1;
        if (kt+1 < 6){
            const int kb = (kt+1)*64;
#pragma unroll
            for (int c=0;c<4;++c){
                __builtin_amdgcn_global_load_lds((const AS1 U32*)(A + aoff[c] + kb),
                    (AS3 U32*)(Ab[cur^1] + (c*256+tid)*8), 16, 0, 0);
                __builtin_amdgcn_global_load_lds((const AS1 U32*)(Bw + boff[c] + kb),
                    (AS3 U32*)(Bb[cur^1] + (c*256+tid)*8), 16, 0, 0);
            }
            asm volatile("s_waitcnt vmcnt(8)" ::: "memory");
        } else {
            asm volatile("s_waitcnt vmcnt(0)" ::: "memory");
        }
        __builtin_amdgcn_sched_barrier(0);
        __builtin_amdgcn_s_barrier();
        __builtin_amdgcn_sched_barrier(0);

#pragma unroll
        for (int kk=0;kk<2;++kk){
            bf8 af[4], bfr[4];
#pragma unroll
            for (int i=0;i<4;++i)
                af[i]  = *(const bf8*)(Ab[cur] + ((kk*4+oct)*128 + wm*64 + i*16 + l15)*8);
#pragma unroll
            for (int j=0;j<4;++j)
                bfr[j] = *(const bf8*)(Bb[cur] + ((kk*4+oct)*128 + wn*64 + j*16 + l15)*8);
            __builtin_amdgcn_s_setprio(1);
#pragma unroll
            for (int i=0;i<4;++i)
#pragma unroll
                for (int j=0;j<4;++j)
                    acc[i][j] = __builtin_amdgcn_mfma_f32_16x16x32_bf16(af[i], bfr[j], acc[i][j], 0, 0, 0);
            __builtin_amdgcn_s_setprio(0);
        }
        __builtin_amdgcn_sched_barrier(0);
        __builtin_amdgcn_s_barrier();
        __builtin_amdgcn_sched_barrier(0);
    }

#pragma unroll
    for (int j=0;j<4;++j){
        const int col = gn0 + wn*64 + j*16 + l15;
        const float sc = s_arr[col];
        const float bi = b_arr[col];
#pragma unroll
        for (int i=0;i<4;++i){
            const int row0 = gm0 + wm*64 + i*16 + oct*4;
#pragma unroll
            for (int r=0;r<4;++r)
                o16[(size_t)(row0+r)*INDIM + col] = f2bf(acc[i][j][r]*sc + bi);
        }
    }
}

// ---------------- proj GEMM 128x128x64, counted-vmcnt double buffer ----------------
__global__ __launch_bounds__(256,2) void k_proj(
    const U16* __restrict__ A, const U16* __restrict__ Bw,
    const float* __restrict__ s_arr, const float* __restrict__ b_arr,
    float* __restrict__ o32)
{
    __shared__ U16 smem[32768];
    U16* Ab[2] = { smem,          smem + 8192 };
    U16* Bb[2] = { smem + 16384,  smem + 24576 };
    const int l   = (blockIdx.x & 7)*49 + (blockIdx.x >> 3);   // bijective (392 = 8*49)
    const int gn0 = (l & 3) * 128;
    const int gm0 = (l >> 2) * 128;
    const int tid  = threadIdx.x;
    const int lane = tid & 63;
    const int w    = tid >> 6;
    const int wm   = w >> 1, wn = w & 1;
    const int l15  = lane & 15, oct = lane >> 4;

    f4 acc[4][4];
#pragma unroll
    for (int i=0;i<4;++i)
#pragma unroll
        for (int j=0;j<4;++j) acc[i][j] = f4zero();

    size_t aoff[4], boff[4];
#pragma unroll
    for (int c=0;c<4;++c){
        int slot = c*256 + tid;
        int row = slot & 127, ch = slot >> 7;
        aoff[c] = (size_t)(gm0 + row)*DHD + ch*8;
        boff[c] = (size_t)(gn0 + row)*DHD + ch*8;
    }

#pragma unroll
    for (int c=0;c<4;++c){
        __builtin_amdgcn_global_load_lds((const AS1 U32*)(A + aoff[c]),
            (AS3 U32*)(Ab[0] + (c*256+tid)*8), 16, 0, 0);
        __builtin_amdgcn_global_load_lds((const AS1 U32*)(Bw + boff[c]),
            (AS3 U32*)(Bb[0] + (c*256+tid)*8), 16, 0, 0);
    }

#pragma unroll
    for (int kt=0; kt<12; ++kt){
        const int cur = kt & 1;
        if (kt+1 < 12){
            const int kb = (kt+1)*64;
#pragma unroll
            for (int c=0;c<4;++c){
                __builtin_amdgcn_global_load_lds((const AS1 U32*)(A + aoff[c] + kb),
                    (AS3 U32*)(Ab[cur^1] + (c*256+tid)*8), 16, 0, 0);
                __builtin_amdgcn_global_load_lds((const AS1 U32*)(Bw + boff[c] + kb),
                    (AS3 U32*)(Bb[cur^1] + (c*256+tid)*8), 16, 0, 0);
            }
            asm volatile("s_waitcnt vmcnt(8)" ::: "memory");
        } else {
            asm volatile("s_waitcnt vmcnt(0)" ::: "memory");
        }
        __builtin_amdgcn_sched_barrier(0);
        __builtin_amdgcn_s_barrier();
        __builtin_amdgcn_sched_barrier(0);

#pragma unroll
        for (int kk=0;kk<2;++kk){
            bf8 af[4], bfr[4];
#pragma unroll
            for (int i=0;i<4;++i)
                af[i]  = *(const bf8*)(Ab[cur] + ((kk*4+oct)*128 + wm*64 + i*16 + l15)*8);
#pragma unroll
            for (int j=0;j<4;++j)
                bfr[j] = *(const bf8*)(Bb[cur] + ((kk*4+oct)*128 + wn*64 + j*16 + l15)*8);
            __builtin_amdgcn_s_setprio(1);
#pragma unroll
            for (int i=0;i<4;++i)
#pragma unroll
                for (int j=0;j<4;++j)
                    acc[i][j] = __builtin_amdgcn_mfma_f32_16x16x32_bf16(af[i], bfr[j], acc[i][j], 0, 0, 0);
            __builtin_amdgcn_s_setprio(0);
        }
        __builtin_amdgcn_sched_barrier(0);
        __builtin_amdgcn_s_barrier();
        __builtin_amdgcn_sched_barrier(0);
    }

#pragma unroll
    for (int j=0;j<4;++j){
        const int col = gn0 + wn*64 + j*16 + l15;
        const float sc = s_arr[col];
        const float bi = b_arr[col];
#pragma unroll
        for (int i=0;i<4;++i){
            const int row0 = gm0 + wm*64 + i*16 + oct*4;
#pragma unroll
            for (int r=0;r<4;++r)
                o32[(size_t)(row0+r)*OUTD + col] = acc[i][j][r]*sc + bi;
        }
    }
}

// ---------------- launch ----------------
extern "C" void kernel_launch(void* const* d_in, const int* in_sizes, int n_in,
                              void* d_out, int out_size, void* d_ws, size_t ws_size,
                              hipStream_t stream)
{
    const float* x    = (const float*)d_in[0];
    const float* kv_w = (const float*)d_in[1];
    const float* kv_g = (const float*)d_in[2];
    const float* kv_b = (const float*)d_in[3];
    const float* kv_m = (const float*)d_in[4];
    const float* kv_v = (const float*)d_in[5];
    const float* q_w  = (const float*)d_in[6];
    const float* q_g  = (const float*)d_in[7];
    const float* q_b  = (const float*)d_in[8];
    const float* q_m  = (const float*)d_in[9];
    const float* q_v  = (const float*)d_in[10];
    const float* pr_w = (const float*)d_in[11];
    const float* pr_g = (const float*)d_in[12];
    const float* pr_b = (const float*)d_in[13];
    const float* pr_m = (const float*)d_in[14];
    const float* pr_v = (const float*)d_in[15];
    const float* ab   = (const float*)d_in[16];
    const int*  idxs  = (const int*)d_in[17];
    const int n_off = in_sizes[16] / NH;

    char* ws = (char*)d_ws;
    size_t off = 0;
    auto alloc = [&](size_t bytes)->char*{
        char* p = ws + off; off += (bytes + 255) & ~(size_t)255; return p;
    };
    U16*   x_bf   = (U16*)  alloc((size_t)BSZ*NPADR*INDIM*2); // 44 MB (padded)
    U16*   xs_bf  = (U16*)  alloc((size_t)BSZ*NQ*INDIM*2);    // 9.6 MB
    U16*   kvw_bf = (U16*)  alloc((size_t)KVH*INDIM*2);
    U16*   qw_bf  = (U16*)  alloc((size_t)INDIM*INDIM*2);
    U16*   prw_bf = (U16*)  alloc((size_t)OUTD*DHD*2);
    float* s_kv   = (float*)alloc(KVH*4);
    float* b_kv   = (float*)alloc(KVH*4);
    float* s_q    = (float*)alloc(INDIM*4);
    float* b_q    = (float*)alloc(INDIM*4);
    float* s_pr   = (float*)alloc(OUTD*4);
    float* b_pr   = (float*)alloc(OUTD*4);
    float* biasf  = (float*)alloc(((size_t)NH*NQ*NTOK + 256)*4);  // +pad for f4 tail reads
    U16*   q_out  = (U16*)  alloc((size_t)BSZ*NQ*INDIM*2);    // 9.6 MB
    U16*   a_out  = (U16*)  alloc((size_t)BSZ*NQ*DHD*2);      // 19.3 MB
    if (off > ws_size) return;  // insufficient workspace: fail visibly (no OOB writes)

    // prep (4 launches)
    {
        int n8 = BSZ*NPADR*INDIM/8;
        k_cast8p<<<(n8+255)/256, 256, 0, stream>>>(x, x_bf, n8);
    }
    {
        int n8 = BSZ*NQ*INDIM/8;
        k_castxs<<<(n8+255)/256, 256, 0, stream>>>(x, xs_bf, n8);
    }
    k_castw<<<(W1C+W2C+W3C+255)/256, 256, 0, stream>>>(kv_w, q_w, pr_w, kvw_bf, qw_bf, prw_bf);
    k_misc<<<BIAS_BLK+BN_BLK, 256, 0, stream>>>(
        ab, idxs, n_off,
        kv_g, kv_b, kv_m, kv_v, q_g, q_b, q_m, q_v, pr_g, pr_b, pr_m, pr_v,
        s_kv, b_kv, s_q, b_q, s_pr, b_pr, biasf);

    // q GEMM: (12544 x 384 x 384) -> bf16 row-major
    {
        dim3 g(INDIM/128, BSZ*NQ/128);
        k_qgemm<<<g, 256, 0, stream>>>(xs_bf, qw_bf, s_q, b_q, q_out);
    }
    // fused kv-GEMM + attention + hard_swish (1 head/block, 2 blocks/CU, XCD-swizzled)
    k_fused<<<BSZ*NH, 256, 0, stream>>>(x_bf, kvw_bf, q_out, s_kv, b_kv, biasf, a_out);
    // proj GEMM: (12544 x 512 x 768) -> f32 out (XCD-swizzled 1-D grid)
    k_proj<<<392, 256, 0, stream>>>(a_out, prw_bf, s_pr, b_pr, (float*)d_out);
}